// Round 2
// baseline (4005.329 us; speedup 1.0000x reference)
//
#include <hip/hip_runtime.h>
#include <hip/hip_bf16.h>

#define CONCAT_F 1137

static __device__ __forceinline__ void atomAddF(float* p, float v) {
  unsafeAtomicAdd(p, v);
}

template <typename MT>
static __device__ __forceinline__ MT toMT(float v);
template <>
__device__ __forceinline__ float toMT<float>(float v) { return v; }
template <>
__device__ __forceinline__ __hip_bfloat16 toMT<__hip_bfloat16>(float v) {
  return __float2bfloat16(v);
}
static __device__ __forceinline__ float fromMT(float v) { return v; }
static __device__ __forceinline__ float fromMT(__hip_bfloat16 v) { return __bfloat162float(v); }

// ---------------- degree / normalization ----------------
__global__ void k_deg_init(float* __restrict__ deg, int n) {
  int i = blockIdx.x * blockDim.x + threadIdx.x;
  if (i < n) deg[i] = 1.0f;  // self-loop contribution
}

__global__ void k_deg_count(const int* __restrict__ dst, float* __restrict__ deg, int E) {
  int e = blockIdx.x * blockDim.x + threadIdx.x;
  if (e < E) atomAddF(&deg[dst[e]], 1.0f);
}

__global__ void k_deg_finish(float* __restrict__ deg, int n) {
  int i = blockIdx.x * blockDim.x + threadIdx.x;
  if (i < n) deg[i] = rsqrtf(deg[i]);  // deg >= 1 always
}

// ---------------- GCN layer: M = dis * (X @ W); AGG initialized with M ------
// wave per row; lane = output feature (64 out features). Safe when AGG == X
// (row read fully into registers before the row is written; waves only touch
// their own rows).
template <typename MT, int K>
__global__ void k_gcn_mm(const float* __restrict__ X, const float* __restrict__ W,
                         const float* __restrict__ dis, MT* __restrict__ M,
                         float* __restrict__ AGG, int n) {
  __shared__ float Ws[K * 64];
  int tid = threadIdx.x;
  for (int j = tid; j < K * 64; j += blockDim.x) Ws[j] = W[j];
  __syncthreads();
  int lane = tid & 63;
  int wid = tid >> 6;
  int row = blockIdx.x * (blockDim.x >> 6) + wid;
  if (row >= n) return;
  float xv = (lane < K) ? X[(long)row * K + lane] : 0.0f;
  float acc = 0.0f;
#pragma unroll 8
  for (int k = 0; k < K; ++k) {
    float xk = __shfl(xv, k, 64);
    acc = fmaf(xk, Ws[k * 64 + lane], acc);
  }
  float v = acc * dis[row];
  long o = (long)row * 64 + lane;
  M[o] = toMT<MT>(v);
  AGG[o] = v;
}

// ---------------- edge aggregation: AGG[dst] += M[src] ----------------------
template <typename MT>
__global__ void k_edge_agg(const int* __restrict__ src, const int* __restrict__ dst,
                           const MT* __restrict__ M, float* __restrict__ AGG, int E) {
  int w = (int)((blockIdx.x * (long)blockDim.x + threadIdx.x) >> 6);
  int lane = threadIdx.x & 63;
  if (w >= E) return;
  int s = src[w];
  int d = dst[w];
  atomAddF(&AGG[(long)d * 64 + lane], fromMT(M[(long)s * 64 + lane]));
}

// ---------------- epilogue: X = relu(AGG * dis + b) -------------------------
__global__ void k_gcn_post(float* __restrict__ AGG, const float* __restrict__ dis,
                           const float* __restrict__ b, int total) {
  int i = blockIdx.x * blockDim.x + threadIdx.x;
  if (i >= total) return;
  int row = i >> 6;
  int f = i & 63;
  float v = fmaf(AGG[i], dis[row], b[f]);
  AGG[i] = v > 0.0f ? v : 0.0f;
}

// ---------------- mean pool over sorted batch (run-length + atomics) --------
__global__ void k_pool8(const float* __restrict__ H, const int* __restrict__ batch,
                        float* __restrict__ sums, float* __restrict__ cnt, int n) {
  int w = (int)((blockIdx.x * (long)blockDim.x + threadIdx.x) >> 6);
  int lane = threadIdx.x & 63;
  int r0 = w * 8;
  if (r0 >= n) return;
  int cur = batch[r0];
  float acc = H[(long)r0 * 64 + lane];
  float c = 1.0f;
  for (int i = 1; i < 8; ++i) {
    int r = r0 + i;
    if (r >= n) break;
    int b = batch[r];
    float v = H[(long)r * 64 + lane];
    if (b == cur) {
      acc += v;
      c += 1.0f;
    } else {
      atomAddF(&sums[(long)cur * 64 + lane], acc);
      if (lane == 0) atomAddF(&cnt[cur], c);
      cur = b;
      acc = v;
      c = 1.0f;
    }
  }
  atomAddF(&sums[(long)cur * 64 + lane], acc);
  if (lane == 0) atomAddF(&cnt[cur], c);
}

// ---------------- drug fc: relu((sums/cnt) @ Wd + bd), 64 -> 128 ------------
__global__ void k_drugfc(const float* __restrict__ sums, const float* __restrict__ cnt,
                         const float* __restrict__ W, const float* __restrict__ b,
                         float* __restrict__ out, int B) {
  __shared__ float ps[64];
  int row = blockIdx.x;
  int tid = threadIdx.x;
  float inv = 1.0f / fmaxf(cnt[row], 1.0f);
  if (tid < 64) ps[tid] = sums[(long)row * 64 + tid] * inv;
  __syncthreads();
  float acc = b[tid];
#pragma unroll 8
  for (int k = 0; k < 64; ++k) acc = fmaf(ps[k], W[k * 128 + tid], acc);
  out[(long)row * 128 + tid] = fmaxf(acc, 0.0f);
}

// ---------------- protein fc: relu(X @ Wp + bp), 979 -> 128 -----------------
__global__ void k_protfc(const float* __restrict__ X, const float* __restrict__ W,
                         const float* __restrict__ bias, float* __restrict__ out, int B) {
  __shared__ float xs[16][979];
  int row0 = blockIdx.x * 16;
  int tid = threadIdx.x;
  for (int r = 0; r < 16; ++r)
    for (int k = tid; k < 979; k += 256) xs[r][k] = X[(long)(row0 + r) * 979 + k];
  __syncthreads();
  int col = tid & 127;
  int rg = (tid >> 7) * 8;
  float acc[8];
  float b = bias[col];
#pragma unroll
  for (int i = 0; i < 8; ++i) acc[i] = b;
  for (int k = 0; k < 979; ++k) {
    float w = W[k * 128 + col];
#pragma unroll
    for (int i = 0; i < 8; ++i) acc[i] = fmaf(xs[rg + i][k], w, acc[i]);
  }
#pragma unroll
  for (int i = 0; i < 8; ++i)
    out[(long)(row0 + rg + i) * 128 + col] = fmaxf(acc[i], 0.0f);
}

// ---------------- concat + LayerNorm ----------------------------------------
__global__ void k_concat_ln(const float* __restrict__ drug, const float* __restrict__ prot,
                            const float* __restrict__ fpp, float* __restrict__ comb, int B) {
  __shared__ float buf[CONCAT_F];
  __shared__ float rs[4], rs2[4];
  int row = blockIdx.x;
  int tid = threadIdx.x;
  float s = 0.0f, s2 = 0.0f;
  for (int j = tid; j < CONCAT_F; j += 256) {
    float v;
    if (j < 128) v = drug[(long)row * 128 + j];
    else if (j < 256) v = prot[(long)row * 128 + (j - 128)];
    else v = fpp[(long)row * 881 + (j - 256)];
    buf[j] = v;
    s += v;
    s2 += v * v;
  }
  for (int o = 32; o; o >>= 1) {
    s += __shfl_down(s, o, 64);
    s2 += __shfl_down(s2, o, 64);
  }
  int lane = tid & 63, wid = tid >> 6;
  if (lane == 0) { rs[wid] = s; rs2[wid] = s2; }
  __syncthreads();
  if (tid == 0) {
    float ts = rs[0] + rs[1] + rs[2] + rs[3];
    float ts2 = rs2[0] + rs2[1] + rs2[2] + rs2[3];
    float mu = ts / (float)CONCAT_F;
    float var = ts2 / (float)CONCAT_F - mu * mu;
    rs[0] = mu;
    rs2[0] = rsqrtf(fmaxf(var, 0.0f) + 1e-5f);
  }
  __syncthreads();
  float mu = rs[0], inv = rs2[0];
  for (int j = tid; j < CONCAT_F; j += 256)
    comb[(long)row * CONCAT_F + j] = (buf[j] - mu) * inv;
}

// ---------------- fc1: relu(X @ W + b), 1137 -> 512 -------------------------
__global__ void k_fc1(const float* __restrict__ X, const float* __restrict__ W,
                      const float* __restrict__ bias, float* __restrict__ out, int B) {
  __shared__ float xs[16][576];
  int row0 = blockIdx.x * 16;
  int tid = threadIdx.x;
  float acc0[16], acc1[16];
  float b0 = bias[tid], b1 = bias[tid + 256];
#pragma unroll
  for (int r = 0; r < 16; ++r) { acc0[r] = b0; acc1[r] = b1; }
  for (int kt = 0; kt < CONCAT_F; kt += 576) {
    int klen = min(576, CONCAT_F - kt);
    __syncthreads();
    for (int r = 0; r < 16; ++r)
      for (int k = tid; k < klen; k += 256)
        xs[r][k] = X[(long)(row0 + r) * CONCAT_F + kt + k];
    __syncthreads();
    for (int k = 0; k < klen; ++k) {
      float w0 = W[(kt + k) * 512 + tid];
      float w1 = W[(kt + k) * 512 + tid + 256];
#pragma unroll
      for (int r = 0; r < 16; ++r) {
        float xv = xs[r][k];
        acc0[r] = fmaf(xv, w0, acc0[r]);
        acc1[r] = fmaf(xv, w1, acc1[r]);
      }
    }
  }
#pragma unroll
  for (int r = 0; r < 16; ++r) {
    out[(long)(row0 + r) * 512 + tid] = fmaxf(acc0[r], 0.0f);
    out[(long)(row0 + r) * 512 + tid + 256] = fmaxf(acc1[r], 0.0f);
  }
}

// ---------------- fc2: relu(X @ W + b), 512 -> 256 --------------------------
__global__ void k_fc2(const float* __restrict__ X, const float* __restrict__ W,
                      const float* __restrict__ bias, float* __restrict__ out, int B) {
  __shared__ float xs[32][512];
  int row0 = blockIdx.x * 32;
  int tid = threadIdx.x;
  for (int r = 0; r < 32; ++r)
    for (int k = tid; k < 512; k += 256) xs[r][k] = X[(long)(row0 + r) * 512 + k];
  __syncthreads();
  float acc[32];
  float b = bias[tid];
#pragma unroll
  for (int r = 0; r < 32; ++r) acc[r] = b;
  for (int k = 0; k < 512; ++k) {
    float w = W[k * 256 + tid];
#pragma unroll
    for (int r = 0; r < 32; ++r) acc[r] = fmaf(xs[r][k], w, acc[r]);
  }
#pragma unroll
  for (int r = 0; r < 32; ++r)
    out[(long)(row0 + r) * 256 + tid] = fmaxf(acc[r], 0.0f);
}

// ---------------- fc3: X @ w + b, 256 -> 1 ----------------------------------
__global__ void k_fc3(const float* __restrict__ X, const float* __restrict__ W,
                      const float* __restrict__ bias, float* __restrict__ out, int B) {
  int w = (int)((blockIdx.x * (long)blockDim.x + threadIdx.x) >> 6);
  int lane = threadIdx.x & 63;
  if (w >= B) return;
  float s = 0.0f;
#pragma unroll
  for (int j = 0; j < 4; ++j) s = fmaf(X[(long)w * 256 + lane + j * 64], W[lane + j * 64], s);
  for (int o = 32; o; o >>= 1) s += __shfl_down(s, o, 64);
  if (lane == 0) out[w] = s + bias[0];
}

// ---------------------------------------------------------------------------
extern "C" void kernel_launch(void* const* d_in, const int* in_sizes, int n_in,
                              void* d_out, int out_size, void* d_ws, size_t ws_size,
                              hipStream_t stream) {
  const float* drug_x = (const float*)d_in[0];
  const int* ei = (const int*)d_in[1];
  const int* batch = (const int*)d_in[2];
  const float* protein_x = (const float*)d_in[3];
  const float* fpp = (const float*)d_in[4];
  const float* W1 = (const float*)d_in[5];
  const float* b1 = (const float*)d_in[6];
  const float* W2 = (const float*)d_in[7];
  const float* b2 = (const float*)d_in[8];
  const float* W3 = (const float*)d_in[9];
  const float* b3 = (const float*)d_in[10];
  const float* Wd = (const float*)d_in[11];
  const float* bd = (const float*)d_in[12];
  const float* Wp = (const float*)d_in[13];
  const float* bp = (const float*)d_in[14];
  const float* Wf1 = (const float*)d_in[15];
  const float* bf1 = (const float*)d_in[16];
  const float* Wf2 = (const float*)d_in[17];
  const float* bf2 = (const float*)d_in[18];
  const float* Wf3 = (const float*)d_in[19];
  const float* bf3 = (const float*)d_in[20];
  float* out = (float*)d_out;

  const int N = in_sizes[0] / 30;
  const int E = in_sizes[1] / 2;
  const int B = in_sizes[4] / 881;

  // ---- workspace budget (floats) ----
  // fp32 path: dis(N) + M(N*64) + AGG(N*64) + sums(B*64) + cnt(B)
  // bf16 path: dis(N) + Mh(N*32 float-equiv) + AGG(N*64) + sums(B*64) + cnt(B)
  const size_t need32 = ((size_t)N * 129 + (size_t)B * 65) * 4;
  const bool fp32path = (ws_size >= need32);

  float* dis = (float*)d_ws;
  size_t off = (size_t)N;  // in floats
  float* Mf = nullptr;
  __hip_bfloat16* Mh = nullptr;
  if (fp32path) {
    Mf = dis + off;
    off += (size_t)N * 64;
  } else {
    Mh = (__hip_bfloat16*)(dis + off);
    off += (size_t)N * 32;
  }
  float* AGG = dis + off;
  off += (size_t)N * 64;
  float* sums = dis + off;
  off += (size_t)B * 64;
  float* cnt = dis + off;

  // dense-tail alias region right after dis (GCN buffers dead by then; <=142MB)
  float* tail = dis + N;
  float* drug = tail;                          // B*128
  float* prot = drug + (size_t)B * 128;        // B*128
  float* comb = prot + (size_t)B * 128;        // B*1137
  float* act1 = comb + (size_t)B * CONCAT_F;   // B*512
  float* act2 = act1 + (size_t)B * 512;        // B*256

  const int* srcIdx = ei;
  const int* dstIdx = ei + E;

  // degrees -> dis
  k_deg_init<<<(N + 255) / 256, 256, 0, stream>>>(dis, N);
  k_deg_count<<<(E + 255) / 256, 256, 0, stream>>>(dstIdx, dis, E);
  k_deg_finish<<<(N + 255) / 256, 256, 0, stream>>>(dis, N);

  int mmBlocks = (N + 3) / 4;
  int edgeBlocks = (E + 3) / 4;
  int postBlocks = (N * 64 + 255) / 256;

  if (fp32path) {
    k_gcn_mm<float, 30><<<mmBlocks, 256, 0, stream>>>(drug_x, W1, dis, Mf, AGG, N);
    k_edge_agg<float><<<edgeBlocks, 256, 0, stream>>>(srcIdx, dstIdx, Mf, AGG, E);
    k_gcn_post<<<postBlocks, 256, 0, stream>>>(AGG, dis, b1, N * 64);
    k_gcn_mm<float, 64><<<mmBlocks, 256, 0, stream>>>(AGG, W2, dis, Mf, AGG, N);
    k_edge_agg<float><<<edgeBlocks, 256, 0, stream>>>(srcIdx, dstIdx, Mf, AGG, E);
    k_gcn_post<<<postBlocks, 256, 0, stream>>>(AGG, dis, b2, N * 64);
    k_gcn_mm<float, 64><<<mmBlocks, 256, 0, stream>>>(AGG, W3, dis, Mf, AGG, N);
    k_edge_agg<float><<<edgeBlocks, 256, 0, stream>>>(srcIdx, dstIdx, Mf, AGG, E);
    k_gcn_post<<<postBlocks, 256, 0, stream>>>(AGG, dis, b3, N * 64);
  } else {
    k_gcn_mm<__hip_bfloat16, 30><<<mmBlocks, 256, 0, stream>>>(drug_x, W1, dis, Mh, AGG, N);
    k_edge_agg<__hip_bfloat16><<<edgeBlocks, 256, 0, stream>>>(srcIdx, dstIdx, Mh, AGG, E);
    k_gcn_post<<<postBlocks, 256, 0, stream>>>(AGG, dis, b1, N * 64);
    k_gcn_mm<__hip_bfloat16, 64><<<mmBlocks, 256, 0, stream>>>(AGG, W2, dis, Mh, AGG, N);
    k_edge_agg<__hip_bfloat16><<<edgeBlocks, 256, 0, stream>>>(srcIdx, dstIdx, Mh, AGG, E);
    k_gcn_post<<<postBlocks, 256, 0, stream>>>(AGG, dis, b2, N * 64);
    k_gcn_mm<__hip_bfloat16, 64><<<mmBlocks, 256, 0, stream>>>(AGG, W3, dis, Mh, AGG, N);
    k_edge_agg<__hip_bfloat16><<<edgeBlocks, 256, 0, stream>>>(srcIdx, dstIdx, Mh, AGG, E);
    k_gcn_post<<<postBlocks, 256, 0, stream>>>(AGG, dis, b3, N * 64);
  }

  // mean pool
  hipMemsetAsync(sums, 0, (size_t)(B * 64 + B) * sizeof(float), stream);
  int poolWaves = (N + 7) / 8;
  k_pool8<<<(poolWaves + 3) / 4, 256, 0, stream>>>(AGG, batch, sums, cnt, N);

  // dense tail
  k_drugfc<<<B, 128, 0, stream>>>(sums, cnt, Wd, bd, drug, B);
  k_protfc<<<B / 16, 256, 0, stream>>>(protein_x, Wp, bp, prot, B);
  k_concat_ln<<<B, 256, 0, stream>>>(drug, prot, fpp, comb, B);
  k_fc1<<<B / 16, 256, 0, stream>>>(comb, Wf1, bf1, act1, B);
  k_fc2<<<B / 32, 256, 0, stream>>>(act1, Wf2, bf2, act2, B);
  k_fc3<<<(B + 3) / 4, 256, 0, stream>>>(act2, Wf3, bf3, out, B);
}

// Round 3
// 2002.684 us; speedup vs baseline: 2.0000x; 2.0000x over previous
//
#include <hip/hip_runtime.h>
#include <hip/hip_bf16.h>

#define CONCAT_F 1137

static __device__ __forceinline__ float bfu2f(unsigned short u) {
  return __uint_as_float(((unsigned)u) << 16);
}
static __device__ __forceinline__ unsigned short f2bfu(float v) {
  __hip_bfloat16 t = __float2bfloat16(v);
  unsigned short u;
  __builtin_memcpy(&u, &t, 2);
  return u;
}

// ================= CSR build =================
__global__ void k_count(const int* __restrict__ dst, int* __restrict__ rs, int E) {
  int e = blockIdx.x * blockDim.x + threadIdx.x;
  if (e < E) atomicAdd(&rs[dst[e]], 1);
}

__global__ void k_disk(const int* __restrict__ cnt, float* __restrict__ dis, int n) {
  int i = blockIdx.x * blockDim.x + threadIdx.x;
  if (i < n) dis[i] = rsqrtf(1.0f + (float)cnt[i]);  // self-loop included
}

__global__ void k_scan_p1(const int* __restrict__ cnt, int* __restrict__ part, int n) {
  __shared__ int red[256];
  int tid = threadIdx.x;
  long base = (long)blockIdx.x * 1024 + tid * 4;
  int s = 0;
#pragma unroll
  for (int i = 0; i < 4; ++i) {
    long j = base + i;
    if (j < n) s += cnt[j];
  }
  red[tid] = s;
  __syncthreads();
  for (int off = 128; off; off >>= 1) {
    if (tid < off) red[tid] += red[tid + off];
    __syncthreads();
  }
  if (tid == 0) part[blockIdx.x] = red[0];
}

__global__ void k_scan_p2(int* __restrict__ part, int nb) {
  __shared__ int a[1024], b_[1024];
  int t = threadIdx.x;
  a[t] = (t < nb) ? part[t] : 0;
  __syncthreads();
  int* s = a;
  int* d = b_;
  for (int off = 1; off < 1024; off <<= 1) {
    d[t] = s[t] + ((t >= off) ? s[t - off] : 0);
    __syncthreads();
    int* tmp = s;
    s = d;
    d = tmp;
  }
  if (t < nb) part[t] = (t == 0) ? 0 : s[t - 1];  // exclusive
}

__global__ void k_scan_p3(int* __restrict__ rs, const int* __restrict__ part, int n) {
  __shared__ int a[256], b_[256];
  int tid = threadIdx.x;
  long base = (long)blockIdx.x * 1024 + tid * 4;
  int v[4];
#pragma unroll
  for (int i = 0; i < 4; ++i) {
    long j = base + i;
    v[i] = (j < n) ? rs[j] : 0;
  }
  a[tid] = v[0] + v[1] + v[2] + v[3];
  __syncthreads();
  int* s = a;
  int* d = b_;
  for (int off = 1; off < 256; off <<= 1) {
    d[tid] = s[tid] + ((tid >= off) ? s[tid - off] : 0);
    __syncthreads();
    int* t2 = s;
    s = d;
    d = t2;
  }
  int run = part[blockIdx.x] + ((tid == 0) ? 0 : s[tid - 1]);
#pragma unroll
  for (int i = 0; i < 4; ++i) {
    long j = base + i;
    if (j < n) {
      rs[j] = run;
      run += v[i];
    }
  }
}

// scatter with rowStart-shift trick: after this, rs[d] == exclusive_end(d)
__global__ void k_scatter(const int* __restrict__ src, const int* __restrict__ dst,
                          int* __restrict__ rs, int* __restrict__ csr, int E) {
  int e = blockIdx.x * blockDim.x + threadIdx.x;
  if (e < E) {
    int pos = atomicAdd(&rs[dst[e]], 1);
    csr[pos] = src[e];
  }
}

// ================= GCN matmul: M = dis*(act(X)@W), bf16 out =================
// 64 rows x 64 cols per block; 4x4 register tile per thread.
// ACT: X is bf16 raw AGG; h = relu(x*dis[row] + bprev[k]). else X f32, identity.
template <int K, bool ACT>
__global__ __launch_bounds__(256) void k_mm(const void* __restrict__ Xv,
                                            const float* __restrict__ W,
                                            const float* __restrict__ bprev,
                                            const float* __restrict__ dis,
                                            unsigned short* __restrict__ M, int n) {
  __shared__ __align__(16) float hT[K][68];  // transposed X tile (stride 68: 2-way = free)
  __shared__ __align__(16) float Ws[K * 64];
  __shared__ float disS[64];
  int tid = threadIdx.x;
  int rb = blockIdx.x * 64;
  for (int j = tid; j < K * 16; j += 256) ((float4*)Ws)[j] = ((const float4*)W)[j];
  if (tid < 64) disS[tid] = (rb + tid < n) ? dis[rb + tid] : 0.0f;
  __syncthreads();
  if constexpr (ACT) {
    const unsigned short* X = (const unsigned short*)Xv;
    int k = tid & 63;
    float bk = bprev[k];
#pragma unroll
    for (int r = tid >> 6; r < 64; r += 4) {
      float h = 0.0f;
      if (rb + r < n) {
        float raw = bfu2f(X[(long)(rb + r) * 64 + k]);
        h = fmaxf(fmaf(raw, disS[r], bk), 0.0f);
      }
      hT[k][r] = h;
    }
  } else {
    const float* X = (const float*)Xv;
    for (int idx = tid; idx < 64 * K; idx += 256) {
      int r = idx / K, k = idx - r * K;
      hT[k][r] = (rb + r < n) ? X[(long)(rb + r) * K + k] : 0.0f;
    }
  }
  __syncthreads();
  int rt = (tid & 15) * 4;
  int ct = (tid >> 4) * 4;
  float acc[4][4] = {};
#pragma unroll 5
  for (int k = 0; k < K; ++k) {
    float4 xr = *(const float4*)&hT[k][rt];
    float4 wr = *(const float4*)&Ws[k * 64 + ct];
    float xa[4] = {xr.x, xr.y, xr.z, xr.w};
    float wa[4] = {wr.x, wr.y, wr.z, wr.w};
#pragma unroll
    for (int i = 0; i < 4; ++i)
#pragma unroll
      for (int j = 0; j < 4; ++j) acc[i][j] = fmaf(xa[i], wa[j], acc[i][j]);
  }
#pragma unroll
  for (int i = 0; i < 4; ++i) {
    int row = rb + rt + i;
    if (row >= n) break;
    float dv = disS[rt + i];
    ushort4 pk;
    pk.x = f2bfu(acc[i][0] * dv);
    pk.y = f2bfu(acc[i][1] * dv);
    pk.z = f2bfu(acc[i][2] * dv);
    pk.w = f2bfu(acc[i][3] * dv);
    *(ushort4*)&M[(long)row * 64 + ct] = pk;
  }
}

// ================= gather: AGG[d] = M[d] + sum_{s in csr[d]} M[s] ===========
// rs is POST-scatter: end(d) = rs[d], start(d) = (d? rs[d-1] : 0)
__global__ void k_gather(const int* __restrict__ rs, const int* __restrict__ csr,
                         const unsigned short* __restrict__ M,
                         unsigned short* __restrict__ AGG, int n) {
  int w = (int)((blockIdx.x * (long)blockDim.x + threadIdx.x) >> 6);
  int lane = threadIdx.x & 63;
  if (w >= n) return;
  int start = (w == 0) ? 0 : rs[w - 1];
  int end = rs[w];
  float a0 = bfu2f(M[(long)w * 64 + lane]);  // self loop
  float a1 = 0.0f;
  int j = start;
  for (; j + 1 < end; j += 2) {
    int s0 = csr[j], s1 = csr[j + 1];
    a0 += bfu2f(M[(long)s0 * 64 + lane]);
    a1 += bfu2f(M[(long)s1 * 64 + lane]);
  }
  if (j < end) a0 += bfu2f(M[(long)csr[j] * 64 + lane]);
  AGG[(long)w * 64 + lane] = f2bfu(a0 + a1);
}

// ============ mean pool (sorted batch) with fused relu(x*dis+b3) ============
__global__ void k_pool8(const unsigned short* __restrict__ H, const float* __restrict__ dis,
                        const float* __restrict__ b3, const int* __restrict__ batch,
                        float* __restrict__ sums, float* __restrict__ cntf, int n) {
  int w = (int)((blockIdx.x * (long)blockDim.x + threadIdx.x) >> 6);
  int lane = threadIdx.x & 63;
  int r0 = w * 8;
  if (r0 >= n) return;
  float bl = b3[lane];
  int cur = batch[r0];
  float acc = fmaxf(fmaf(bfu2f(H[(long)r0 * 64 + lane]), dis[r0], bl), 0.0f);
  float c = 1.0f;
  for (int i = 1; i < 8; ++i) {
    int r = r0 + i;
    if (r >= n) break;
    int b = batch[r];
    float v = fmaxf(fmaf(bfu2f(H[(long)r * 64 + lane]), dis[r], bl), 0.0f);
    if (b == cur) {
      acc += v;
      c += 1.0f;
    } else {
      unsafeAtomicAdd(&sums[(long)cur * 64 + lane], acc);
      if (lane == 0) unsafeAtomicAdd(&cntf[cur], c);
      cur = b;
      acc = v;
      c = 1.0f;
    }
  }
  unsafeAtomicAdd(&sums[(long)cur * 64 + lane], acc);
  if (lane == 0) unsafeAtomicAdd(&cntf[cur], c);
}

// ================= dense tail (unchanged from round 2) ======================
__global__ void k_drugfc(const float* __restrict__ sums, const float* __restrict__ cnt,
                         const float* __restrict__ W, const float* __restrict__ b,
                         float* __restrict__ out, int B) {
  __shared__ float ps[64];
  int row = blockIdx.x;
  int tid = threadIdx.x;
  float inv = 1.0f / fmaxf(cnt[row], 1.0f);
  if (tid < 64) ps[tid] = sums[(long)row * 64 + tid] * inv;
  __syncthreads();
  float acc = b[tid];
#pragma unroll 8
  for (int k = 0; k < 64; ++k) acc = fmaf(ps[k], W[k * 128 + tid], acc);
  out[(long)row * 128 + tid] = fmaxf(acc, 0.0f);
}

__global__ void k_protfc(const float* __restrict__ X, const float* __restrict__ W,
                         const float* __restrict__ bias, float* __restrict__ out, int B) {
  __shared__ float xs[16][979];
  int row0 = blockIdx.x * 16;
  int tid = threadIdx.x;
  for (int r = 0; r < 16; ++r)
    for (int k = tid; k < 979; k += 256) xs[r][k] = X[(long)(row0 + r) * 979 + k];
  __syncthreads();
  int col = tid & 127;
  int rg = (tid >> 7) * 8;
  float acc[8];
  float b = bias[col];
#pragma unroll
  for (int i = 0; i < 8; ++i) acc[i] = b;
  for (int k = 0; k < 979; ++k) {
    float w = W[k * 128 + col];
#pragma unroll
    for (int i = 0; i < 8; ++i) acc[i] = fmaf(xs[rg + i][k], w, acc[i]);
  }
#pragma unroll
  for (int i = 0; i < 8; ++i)
    out[(long)(row0 + rg + i) * 128 + col] = fmaxf(acc[i], 0.0f);
}

__global__ void k_concat_ln(const float* __restrict__ drug, const float* __restrict__ prot,
                            const float* __restrict__ fpp, float* __restrict__ comb, int B) {
  __shared__ float buf[CONCAT_F];
  __shared__ float rs[4], rs2[4];
  int row = blockIdx.x;
  int tid = threadIdx.x;
  float s = 0.0f, s2 = 0.0f;
  for (int j = tid; j < CONCAT_F; j += 256) {
    float v;
    if (j < 128) v = drug[(long)row * 128 + j];
    else if (j < 256) v = prot[(long)row * 128 + (j - 128)];
    else v = fpp[(long)row * 881 + (j - 256)];
    buf[j] = v;
    s += v;
    s2 += v * v;
  }
  for (int o = 32; o; o >>= 1) {
    s += __shfl_down(s, o, 64);
    s2 += __shfl_down(s2, o, 64);
  }
  int lane = tid & 63, wid = tid >> 6;
  if (lane == 0) { rs[wid] = s; rs2[wid] = s2; }
  __syncthreads();
  if (tid == 0) {
    float ts = rs[0] + rs[1] + rs[2] + rs[3];
    float ts2 = rs2[0] + rs2[1] + rs2[2] + rs2[3];
    float mu = ts / (float)CONCAT_F;
    float var = ts2 / (float)CONCAT_F - mu * mu;
    rs[0] = mu;
    rs2[0] = rsqrtf(fmaxf(var, 0.0f) + 1e-5f);
  }
  __syncthreads();
  float mu = rs[0], inv = rs2[0];
  for (int j = tid; j < CONCAT_F; j += 256)
    comb[(long)row * CONCAT_F + j] = (buf[j] - mu) * inv;
}

__global__ void k_fc1(const float* __restrict__ X, const float* __restrict__ W,
                      const float* __restrict__ bias, float* __restrict__ out, int B) {
  __shared__ float xs[16][576];
  int row0 = blockIdx.x * 16;
  int tid = threadIdx.x;
  float acc0[16], acc1[16];
  float b0 = bias[tid], b1 = bias[tid + 256];
#pragma unroll
  for (int r = 0; r < 16; ++r) { acc0[r] = b0; acc1[r] = b1; }
  for (int kt = 0; kt < CONCAT_F; kt += 576) {
    int klen = min(576, CONCAT_F - kt);
    __syncthreads();
    for (int r = 0; r < 16; ++r)
      for (int k = tid; k < klen; k += 256)
        xs[r][k] = X[(long)(row0 + r) * CONCAT_F + kt + k];
    __syncthreads();
    for (int k = 0; k < klen; ++k) {
      float w0 = W[(kt + k) * 512 + tid];
      float w1 = W[(kt + k) * 512 + tid + 256];
#pragma unroll
      for (int r = 0; r < 16; ++r) {
        float xv = xs[r][k];
        acc0[r] = fmaf(xv, w0, acc0[r]);
        acc1[r] = fmaf(xv, w1, acc1[r]);
      }
    }
  }
#pragma unroll
  for (int r = 0; r < 16; ++r) {
    out[(long)(row0 + r) * 512 + tid] = fmaxf(acc0[r], 0.0f);
    out[(long)(row0 + r) * 512 + tid + 256] = fmaxf(acc1[r], 0.0f);
  }
}

__global__ void k_fc2(const float* __restrict__ X, const float* __restrict__ W,
                      const float* __restrict__ bias, float* __restrict__ out, int B) {
  __shared__ float xs[32][512];
  int row0 = blockIdx.x * 32;
  int tid = threadIdx.x;
  for (int r = 0; r < 32; ++r)
    for (int k = tid; k < 512; k += 256) xs[r][k] = X[(long)(row0 + r) * 512 + k];
  __syncthreads();
  float acc[32];
  float b = bias[tid];
#pragma unroll
  for (int r = 0; r < 32; ++r) acc[r] = b;
  for (int k = 0; k < 512; ++k) {
    float w = W[k * 256 + tid];
#pragma unroll
    for (int r = 0; r < 32; ++r) acc[r] = fmaf(xs[r][k], w, acc[r]);
  }
#pragma unroll
  for (int r = 0; r < 32; ++r)
    out[(long)(row0 + r) * 256 + tid] = fmaxf(acc[r], 0.0f);
}

__global__ void k_fc3(const float* __restrict__ X, const float* __restrict__ W,
                      const float* __restrict__ bias, float* __restrict__ out, int B) {
  int w = (int)((blockIdx.x * (long)blockDim.x + threadIdx.x) >> 6);
  int lane = threadIdx.x & 63;
  if (w >= B) return;
  float s = 0.0f;
#pragma unroll
  for (int j = 0; j < 4; ++j) s = fmaf(X[(long)w * 256 + lane + j * 64], W[lane + j * 64], s);
  for (int o = 32; o; o >>= 1) s += __shfl_down(s, o, 64);
  if (lane == 0) out[w] = s + bias[0];
}

// ---------------------------------------------------------------------------
extern "C" void kernel_launch(void* const* d_in, const int* in_sizes, int n_in,
                              void* d_out, int out_size, void* d_ws, size_t ws_size,
                              hipStream_t stream) {
  const float* drug_x = (const float*)d_in[0];
  const int* ei = (const int*)d_in[1];
  const int* batch = (const int*)d_in[2];
  const float* protein_x = (const float*)d_in[3];
  const float* fpp = (const float*)d_in[4];
  const float* W1 = (const float*)d_in[5];
  const float* b1 = (const float*)d_in[6];
  const float* W2 = (const float*)d_in[7];
  const float* b2 = (const float*)d_in[8];
  const float* W3 = (const float*)d_in[9];
  const float* b3 = (const float*)d_in[10];
  const float* Wd = (const float*)d_in[11];
  const float* bd = (const float*)d_in[12];
  const float* Wp = (const float*)d_in[13];
  const float* bp = (const float*)d_in[14];
  const float* Wf1 = (const float*)d_in[15];
  const float* bf1 = (const float*)d_in[16];
  const float* Wf2 = (const float*)d_in[17];
  const float* bf2 = (const float*)d_in[18];
  const float* Wf3 = (const float*)d_in[19];
  const float* bf3 = (const float*)d_in[20];
  float* out = (float*)d_out;

  const int N = in_sizes[0] / 30;
  const int E = in_sizes[1] / 2;
  const int B = in_sizes[4] / 881;

  // ---- workspace layout (4-byte words) ----
  // rs(N+1) | dis(N) | csr(E) | [pad to even] | M bf16(32N) | AGG bf16(32N) |
  // sums(64B) | cntf(B) | part(1024)        total ~151 MB
  int* rs = (int*)d_ws;
  float* dis = (float*)d_ws + ((size_t)N + 1);
  int* csr = (int*)d_ws + (2 * (size_t)N + 1);
  size_t oM = 2 * (size_t)N + 2 + (size_t)E;  // even word offset -> 8B aligned
  unsigned short* M = (unsigned short*)((float*)d_ws + oM);
  unsigned short* AGG = M + (size_t)N * 64;
  float* sums = (float*)d_ws + (oM + 64 * (size_t)N);
  float* cntf = sums + (size_t)B * 64;
  int* part = (int*)(cntf + B);
  // dense tail aliases offset 0 (all GCN buffers dead by then; ends before sums)
  float* tail = (float*)d_ws;
  float* drug = tail;                          // B*128
  float* prot = drug + (size_t)B * 128;        // B*128
  float* comb = prot + (size_t)B * 128;        // B*1137
  float* act1 = comb + (size_t)B * CONCAT_F;   // B*512
  float* act2 = act1 + (size_t)B * 512;        // B*256

  const int* srcIdx = ei;
  const int* dstIdx = ei + E;

  // ---- CSR build + degree ----
  hipMemsetAsync(rs, 0, ((size_t)N + 1) * sizeof(int), stream);
  k_count<<<(E + 255) / 256, 256, 0, stream>>>(dstIdx, rs, E);
  k_disk<<<(N + 255) / 256, 256, 0, stream>>>(rs, dis, N);
  int NB = (N + 1023) / 1024;
  k_scan_p1<<<NB, 256, 0, stream>>>(rs, part, N);
  k_scan_p2<<<1, 1024, 0, stream>>>(part, NB);
  k_scan_p3<<<NB, 256, 0, stream>>>(rs, part, N);
  k_scatter<<<(E + 255) / 256, 256, 0, stream>>>(srcIdx, dstIdx, rs, csr, E);

  // ---- GCN layers ----
  int mmBlocks = (N + 63) / 64;
  int gatherBlocks = (N + 3) / 4;
  k_mm<30, false><<<mmBlocks, 256, 0, stream>>>(drug_x, W1, nullptr, dis, M, N);
  k_gather<<<gatherBlocks, 256, 0, stream>>>(rs, csr, M, AGG, N);
  k_mm<64, true><<<mmBlocks, 256, 0, stream>>>(AGG, W2, b1, dis, M, N);
  k_gather<<<gatherBlocks, 256, 0, stream>>>(rs, csr, M, AGG, N);
  k_mm<64, true><<<mmBlocks, 256, 0, stream>>>(AGG, W3, b2, dis, M, N);
  k_gather<<<gatherBlocks, 256, 0, stream>>>(rs, csr, M, AGG, N);

  // ---- mean pool (fused final relu) ----
  hipMemsetAsync(sums, 0, ((size_t)B * 64 + B) * sizeof(float), stream);
  int poolWaves = (N + 7) / 8;
  k_pool8<<<(poolWaves + 3) / 4, 256, 0, stream>>>(AGG, dis, b3, batch, sums, cntf, N);

  // ---- dense tail ----
  k_drugfc<<<B, 128, 0, stream>>>(sums, cntf, Wd, bd, drug, B);
  k_protfc<<<B / 16, 256, 0, stream>>>(protein_x, Wp, bp, prot, B);
  k_concat_ln<<<B, 256, 0, stream>>>(drug, prot, fpp, comb, B);
  k_fc1<<<B / 16, 256, 0, stream>>>(comb, Wf1, bf1, act1, B);
  k_fc2<<<B / 32, 256, 0, stream>>>(act1, Wf2, bf2, act2, B);
  k_fc3<<<(B + 3) / 4, 256, 0, stream>>>(act2, Wf3, bf3, out, B);
}

// Round 5
// 1819.743 us; speedup vs baseline: 2.2010x; 1.1005x over previous
//
#include <hip/hip_runtime.h>
#include <hip/hip_bf16.h>

#define CONCAT_F 1137
#define CONCAT_P 1152  // padded to multiple of 32 for bf16 MFMA GEMM

typedef __attribute__((ext_vector_type(8))) short bf16x8;
typedef __attribute__((ext_vector_type(4))) float f32x4;

static __device__ __forceinline__ float bfu2f(unsigned short u) {
  return __uint_as_float(((unsigned)u) << 16);
}
static __device__ __forceinline__ unsigned short f2bfu(float v) {
  __hip_bfloat16 t = __float2bfloat16(v);
  unsigned short u;
  __builtin_memcpy(&u, &t, 2);
  return u;
}

// ================= CSR build =================
__global__ void k_count(const int* __restrict__ dst, int* __restrict__ rs, int E) {
  int e = blockIdx.x * blockDim.x + threadIdx.x;
  if (e < E) atomicAdd(&rs[dst[e]], 1);
}

__global__ void k_disk(const int* __restrict__ cnt, float* __restrict__ dis, int n) {
  int i = blockIdx.x * blockDim.x + threadIdx.x;
  if (i < n) dis[i] = rsqrtf(1.0f + (float)cnt[i]);  // self-loop included
}

__global__ void k_scan_p1(const int* __restrict__ cnt, int* __restrict__ part, int n) {
  __shared__ int red[256];
  int tid = threadIdx.x;
  long base = (long)blockIdx.x * 1024 + tid * 4;
  int s = 0;
#pragma unroll
  for (int i = 0; i < 4; ++i) {
    long j = base + i;
    if (j < n) s += cnt[j];
  }
  red[tid] = s;
  __syncthreads();
  for (int off = 128; off; off >>= 1) {
    if (tid < off) red[tid] += red[tid + off];
    __syncthreads();
  }
  if (tid == 0) part[blockIdx.x] = red[0];
}

__global__ void k_scan_p2(int* __restrict__ part, int nb) {
  __shared__ int a[1024], b_[1024];
  int t = threadIdx.x;
  a[t] = (t < nb) ? part[t] : 0;
  __syncthreads();
  int* s = a;
  int* d = b_;
  for (int off = 1; off < 1024; off <<= 1) {
    d[t] = s[t] + ((t >= off) ? s[t - off] : 0);
    __syncthreads();
    int* tmp = s;
    s = d;
    d = tmp;
  }
  if (t < nb) part[t] = (t == 0) ? 0 : s[t - 1];  // exclusive
}

__global__ void k_scan_p3(int* __restrict__ rs, const int* __restrict__ part, int n) {
  __shared__ int a[256], b_[256];
  int tid = threadIdx.x;
  long base = (long)blockIdx.x * 1024 + tid * 4;
  int v[4];
#pragma unroll
  for (int i = 0; i < 4; ++i) {
    long j = base + i;
    v[i] = (j < n) ? rs[j] : 0;
  }
  a[tid] = v[0] + v[1] + v[2] + v[3];
  __syncthreads();
  int* s = a;
  int* d = b_;
  for (int off = 1; off < 256; off <<= 1) {
    d[tid] = s[tid] + ((tid >= off) ? s[tid - off] : 0);
    __syncthreads();
    int* t2 = s;
    s = d;
    d = t2;
  }
  int run = part[blockIdx.x] + ((tid == 0) ? 0 : s[tid - 1]);
#pragma unroll
  for (int i = 0; i < 4; ++i) {
    long j = base + i;
    if (j < n) {
      rs[j] = run;
      run += v[i];
    }
  }
}

// scatter with rowStart-shift trick: after this, rs[d] == exclusive_end(d)
__global__ void k_scatter(const int* __restrict__ src, const int* __restrict__ dst,
                          int* __restrict__ rs, int* __restrict__ csr, int E) {
  int e = blockIdx.x * blockDim.x + threadIdx.x;
  if (e < E) {
    int pos = atomicAdd(&rs[dst[e]], 1);
    csr[pos] = src[e];
  }
}

// ================= GCN matmul: M = dis*(act(X)@W), bf16 out =================
template <int K, bool ACT>
__global__ __launch_bounds__(256) void k_mm(const void* __restrict__ Xv,
                                            const float* __restrict__ W,
                                            const float* __restrict__ bprev,
                                            const float* __restrict__ dis,
                                            unsigned short* __restrict__ M, int n) {
  __shared__ __align__(16) float hT[K][68];
  __shared__ __align__(16) float Ws[K * 64];
  __shared__ float disS[64];
  int tid = threadIdx.x;
  int rb = blockIdx.x * 64;
  for (int j = tid; j < K * 16; j += 256) ((float4*)Ws)[j] = ((const float4*)W)[j];
  if (tid < 64) disS[tid] = (rb + tid < n) ? dis[rb + tid] : 0.0f;
  __syncthreads();
  if constexpr (ACT) {
    const unsigned short* X = (const unsigned short*)Xv;
    int k = tid & 63;
    float bk = bprev[k];
#pragma unroll
    for (int r = tid >> 6; r < 64; r += 4) {
      float h = 0.0f;
      if (rb + r < n) {
        float raw = bfu2f(X[(long)(rb + r) * 64 + k]);
        h = fmaxf(fmaf(raw, disS[r], bk), 0.0f);
      }
      hT[k][r] = h;
    }
  } else {
    const float* X = (const float*)Xv;
    for (int idx = tid; idx < 64 * K; idx += 256) {
      int r = idx / K, k = idx - r * K;
      hT[k][r] = (rb + r < n) ? X[(long)(rb + r) * K + k] : 0.0f;
    }
  }
  __syncthreads();
  int rt = (tid & 15) * 4;
  int ct = (tid >> 4) * 4;
  float acc[4][4] = {};
#pragma unroll 5
  for (int k = 0; k < K; ++k) {
    float4 xr = *(const float4*)&hT[k][rt];
    float4 wr = *(const float4*)&Ws[k * 64 + ct];
    float xa[4] = {xr.x, xr.y, xr.z, xr.w};
    float wa[4] = {wr.x, wr.y, wr.z, wr.w};
#pragma unroll
    for (int i = 0; i < 4; ++i)
#pragma unroll
      for (int j = 0; j < 4; ++j) acc[i][j] = fmaf(xa[i], wa[j], acc[i][j]);
  }
#pragma unroll
  for (int i = 0; i < 4; ++i) {
    int row = rb + rt + i;
    if (row >= n) break;
    float dv = disS[rt + i];
    ushort4 pk;
    pk.x = f2bfu(acc[i][0] * dv);
    pk.y = f2bfu(acc[i][1] * dv);
    pk.z = f2bfu(acc[i][2] * dv);
    pk.w = f2bfu(acc[i][3] * dv);
    *(ushort4*)&M[(long)row * 64 + ct] = pk;
  }
}

// ================= gather: AGG[d] = M[d] + sum_{s in csr[d]} M[s] ===========
__global__ void k_gather(const int* __restrict__ rs, const int* __restrict__ csr,
                         const unsigned short* __restrict__ M,
                         unsigned short* __restrict__ AGG, int n) {
  int w = (int)((blockIdx.x * (long)blockDim.x + threadIdx.x) >> 6);
  int lane = threadIdx.x & 63;
  if (w >= n) return;
  int start = (w == 0) ? 0 : rs[w - 1];
  int end = rs[w];
  float a0 = bfu2f(M[(long)w * 64 + lane]);  // self loop
  float a1 = 0.0f;
  int j = start;
  for (; j + 1 < end; j += 2) {
    int s0 = csr[j], s1 = csr[j + 1];
    a0 += bfu2f(M[(long)s0 * 64 + lane]);
    a1 += bfu2f(M[(long)s1 * 64 + lane]);
  }
  if (j < end) a0 += bfu2f(M[(long)csr[j] * 64 + lane]);
  AGG[(long)w * 64 + lane] = f2bfu(a0 + a1);
}

// ============ mean pool (sorted batch) with fused relu(x*dis+b3) ============
__global__ void k_pool8(const unsigned short* __restrict__ H, const float* __restrict__ dis,
                        const float* __restrict__ b3, const int* __restrict__ batch,
                        float* __restrict__ sums, float* __restrict__ cntf, int n) {
  int w = (int)((blockIdx.x * (long)blockDim.x + threadIdx.x) >> 6);
  int lane = threadIdx.x & 63;
  int r0 = w * 8;
  if (r0 >= n) return;
  float bl = b3[lane];
  int cur = batch[r0];
  float acc = fmaxf(fmaf(bfu2f(H[(long)r0 * 64 + lane]), dis[r0], bl), 0.0f);
  float c = 1.0f;
  for (int i = 1; i < 8; ++i) {
    int r = r0 + i;
    if (r >= n) break;
    int b = batch[r];
    float v = fmaxf(fmaf(bfu2f(H[(long)r * 64 + lane]), dis[r], bl), 0.0f);
    if (b == cur) {
      acc += v;
      c += 1.0f;
    } else {
      unsafeAtomicAdd(&sums[(long)cur * 64 + lane], acc);
      if (lane == 0) unsafeAtomicAdd(&cntf[cur], c);
      cur = b;
      acc = v;
      c = 1.0f;
    }
  }
  unsafeAtomicAdd(&sums[(long)cur * 64 + lane], acc);
  if (lane == 0) unsafeAtomicAdd(&cntf[cur], c);
}

// ================= drug fc: relu((sums/cnt) @ Wd + bd), 64 -> 128 ===========
__global__ void k_drugfc(const float* __restrict__ sums, const float* __restrict__ cnt,
                         const float* __restrict__ W, const float* __restrict__ b,
                         float* __restrict__ out, int B) {
  __shared__ float ps[64];
  int row = blockIdx.x;
  int tid = threadIdx.x;
  float inv = 1.0f / fmaxf(cnt[row], 1.0f);
  if (tid < 64) ps[tid] = sums[(long)row * 64 + tid] * inv;
  __syncthreads();
  float acc = b[tid];
#pragma unroll 8
  for (int k = 0; k < 64; ++k) acc = fmaf(ps[k], W[k * 128 + tid], acc);
  out[(long)row * 128 + tid] = fmaxf(acc, 0.0f);
}

// ======== bf16 MFMA GEMM: C = relu(A @ W + bias), 128x128 tile, BK=32 =======
// A: [M x lda] (f32 if !VECA, bf16-bits if VECA; VECA requires lda%32==0),
// W: [K x N] f32 (guarded to K rows), C: [M x N] (OT = float or bf16-bits).
// 4 waves: wave wid computes rows [wid*32, wid*32+32) x all 128 cols.
// LDS: As/Bs [128 rows][32 bf16] with XOR swizzle byte^=(row&7)<<4 (bijective).
template <bool VECA, typename OT>
__global__ __launch_bounds__(256) void k_gemm_relu(
    const void* __restrict__ Av, const float* __restrict__ W,
    const float* __restrict__ bias, OT* __restrict__ C,
    int N, int K, int lda, int nsteps) {
  __shared__ __align__(16) unsigned short As[128 * 32];
  __shared__ __align__(16) unsigned short Bs[128 * 32];
  const int tid = threadIdx.x;
  const int lane = tid & 63;
  const int wid = tid >> 6;
  const int bm = blockIdx.x * 128;
  const int bn = blockIdx.y * 128;
  const int kb = lane >> 4, fr = lane & 15;

  f32x4 acc[2][8];
#pragma unroll
  for (int i = 0; i < 2; ++i)
#pragma unroll
    for (int j = 0; j < 8; ++j) acc[i][j] = f32x4{0.f, 0.f, 0.f, 0.f};

  // loop-invariant swizzled LDS byte offsets (read side)
  int aOff[2], bOff[8];
#pragma unroll
  for (int mi = 0; mi < 2; ++mi) {
    int r = wid * 32 + mi * 16 + fr;
    aOff[mi] = (r * 64 + kb * 16) ^ ((r & 7) << 4);
  }
#pragma unroll
  for (int ni = 0; ni < 8; ++ni) {
    int nr = ni * 16 + fr;
    bOff[ni] = (nr * 64 + kb * 16) ^ ((nr & 7) << 4);
  }
  // write side: A tile — 128 rows x 4 chunks(16B); 2 chunks per thread
  const int arow = tid >> 1;
  int aWOff[2];
#pragma unroll
  for (int p = 0; p < 2; ++p) {
    int cb = (tid & 1) * 2 + p;
    aWOff[p] = ((arow * 64 + cb * 16) ^ ((arow & 7) << 4));
  }
  const int bn_ = tid & 127, bkb0 = tid >> 7;

  for (int s = 0; s < nsteps; ++s) {
    __syncthreads();
    const int k0 = s * 32;
    // ---- stage A tile: 2 chunks of 8 bf16 per thread (all 32 k covered)
#pragma unroll
    for (int p = 0; p < 2; ++p) {
      int cb = (tid & 1) * 2 + p;
      if constexpr (VECA) {
        const unsigned short* Au = (const unsigned short*)Av;
        bf16x8 v = *(const bf16x8*)(Au + (size_t)(bm + arow) * lda + k0 + cb * 8);
        *(bf16x8*)((char*)As + aWOff[p]) = v;
      } else {
        const float* Af = (const float*)Av;
        const float* sp = Af + (size_t)(bm + arow) * lda + k0 + cb * 8;
        bf16x8 v;
#pragma unroll
        for (int i = 0; i < 8; ++i) {
          int gk = k0 + cb * 8 + i;
          float x = (gk < K) ? sp[i] : 0.f;
          v[i] = (short)f2bfu(x);
        }
        *(bf16x8*)((char*)As + aWOff[p]) = v;
      }
    }
    // ---- stage B tile = W^T (coalesced reads: lanes span consecutive n)
#pragma unroll
    for (int p = 0; p < 2; ++p) {
      int kbb = bkb0 * 2 + p;
      bf16x8 v;
#pragma unroll
      for (int i = 0; i < 8; ++i) {
        int gk = k0 + kbb * 8 + i;
        float x = (gk < K) ? W[(size_t)gk * N + bn + bn_] : 0.f;
        v[i] = (short)f2bfu(x);
      }
      int off = ((bn_ * 64 + kbb * 16) ^ ((bn_ & 7) << 4));
      *(bf16x8*)((char*)Bs + off) = v;
    }
    __syncthreads();
    // ---- 16 MFMAs per wave
    bf16x8 a0 = *(const bf16x8*)((char*)As + aOff[0]);
    bf16x8 a1 = *(const bf16x8*)((char*)As + aOff[1]);
#pragma unroll
    for (int ni = 0; ni < 8; ++ni) {
      bf16x8 b = *(const bf16x8*)((char*)Bs + bOff[ni]);
      acc[0][ni] = __builtin_amdgcn_mfma_f32_16x16x32_bf16(a0, b, acc[0][ni], 0, 0, 0);
      acc[1][ni] = __builtin_amdgcn_mfma_f32_16x16x32_bf16(a1, b, acc[1][ni], 0, 0, 0);
    }
  }
  // ---- epilogue: bias + relu; C/D layout col=lane&15, row=(lane>>4)*4+reg
  float bv[8];
#pragma unroll
  for (int ni = 0; ni < 8; ++ni) bv[ni] = bias[bn + ni * 16 + fr];
#pragma unroll
  for (int mi = 0; mi < 2; ++mi)
#pragma unroll
    for (int ni = 0; ni < 8; ++ni)
#pragma unroll
      for (int r = 0; r < 4; ++r) {
        int row = bm + wid * 32 + mi * 16 + kb * 4 + r;
        int col = bn + ni * 16 + fr;
        float x = fmaxf(acc[mi][ni][r] + bv[ni], 0.f);
        if constexpr (__hip_internal::is_same<OT, float>::value) {
          C[(size_t)row * N + col] = x;
        } else {
          C[(size_t)row * N + col] = f2bfu(x);
        }
      }
}

// ---------- concat + LayerNorm, bf16 output padded to CONCAT_P --------------
__global__ void k_concat_ln(const float* __restrict__ drug, const float* __restrict__ prot,
                            const float* __restrict__ fpp, unsigned short* __restrict__ comb,
                            int B) {
  __shared__ float buf[CONCAT_F];
  __shared__ float rs[4], rs2[4];
  int row = blockIdx.x;
  int tid = threadIdx.x;
  float s = 0.0f, s2 = 0.0f;
  for (int j = tid; j < CONCAT_F; j += 256) {
    float v;
    if (j < 128) v = drug[(long)row * 128 + j];
    else if (j < 256) v = prot[(long)row * 128 + (j - 128)];
    else v = fpp[(long)row * 881 + (j - 256)];
    buf[j] = v;
    s += v;
    s2 += v * v;
  }
  for (int o = 32; o; o >>= 1) {
    s += __shfl_down(s, o, 64);
    s2 += __shfl_down(s2, o, 64);
  }
  int lane = tid & 63, wid = tid >> 6;
  if (lane == 0) { rs[wid] = s; rs2[wid] = s2; }
  __syncthreads();
  if (tid == 0) {
    float ts = rs[0] + rs[1] + rs[2] + rs[3];
    float ts2 = rs2[0] + rs2[1] + rs2[2] + rs2[3];
    float mu = ts / (float)CONCAT_F;
    float var = ts2 / (float)CONCAT_F - mu * mu;
    rs[0] = mu;
    rs2[0] = rsqrtf(fmaxf(var, 0.0f) + 1e-5f);
  }
  __syncthreads();
  float mu = rs[0], inv = rs2[0];
  for (int j = tid; j < CONCAT_P; j += 256) {
    unsigned short o = (j < CONCAT_F) ? f2bfu((buf[j] - mu) * inv) : 0;
    comb[(long)row * CONCAT_P + j] = o;
  }
}

// ---------------- fc3: X @ w + b, 256 -> 1 ----------------------------------
__global__ void k_fc3(const float* __restrict__ X, const float* __restrict__ W,
                      const float* __restrict__ bias, float* __restrict__ out, int B) {
  int w = (int)((blockIdx.x * (long)blockDim.x + threadIdx.x) >> 6);
  int lane = threadIdx.x & 63;
  if (w >= B) return;
  float s = 0.0f;
#pragma unroll
  for (int j = 0; j < 4; ++j) s = fmaf(X[(long)w * 256 + lane + j * 64], W[lane + j * 64], s);
  for (int o = 32; o; o >>= 1) s += __shfl_down(s, o, 64);
  if (lane == 0) out[w] = s + bias[0];
}

// ---------------------------------------------------------------------------
extern "C" void kernel_launch(void* const* d_in, const int* in_sizes, int n_in,
                              void* d_out, int out_size, void* d_ws, size_t ws_size,
                              hipStream_t stream) {
  const float* drug_x = (const float*)d_in[0];
  const int* ei = (const int*)d_in[1];
  const int* batch = (const int*)d_in[2];
  const float* protein_x = (const float*)d_in[3];
  const float* fpp = (const float*)d_in[4];
  const float* W1 = (const float*)d_in[5];
  const float* b1 = (const float*)d_in[6];
  const float* W2 = (const float*)d_in[7];
  const float* b2 = (const float*)d_in[8];
  const float* W3 = (const float*)d_in[9];
  const float* b3 = (const float*)d_in[10];
  const float* Wd = (const float*)d_in[11];
  const float* bd = (const float*)d_in[12];
  const float* Wp = (const float*)d_in[13];
  const float* bp = (const float*)d_in[14];
  const float* Wf1 = (const float*)d_in[15];
  const float* bf1 = (const float*)d_in[16];
  const float* Wf2 = (const float*)d_in[17];
  const float* bf2 = (const float*)d_in[18];
  const float* Wf3 = (const float*)d_in[19];
  const float* bf3 = (const float*)d_in[20];
  float* out = (float*)d_out;

  const int N = in_sizes[0] / 30;
  const int E = in_sizes[1] / 2;
  const int B = in_sizes[4] / 881;

  // ---- GCN-phase workspace (words) ----
  int* rs = (int*)d_ws;
  float* dis = (float*)d_ws + ((size_t)N + 1);
  int* csr = (int*)d_ws + (2 * (size_t)N + 1);
  size_t oM = 2 * (size_t)N + 2 + (size_t)E;
  unsigned short* M = (unsigned short*)((float*)d_ws + oM);
  unsigned short* AGG = M + (size_t)N * 64;
  float* sums = (float*)d_ws + (oM + 64 * (size_t)N);
  float* cntf = sums + (size_t)B * 64;
  int* part = (int*)(cntf + B);
  // ---- dense-tail aliases at offset 0 (GCN buffers dead; ends << sums) ----
  float* tail = (float*)d_ws;
  float* drug = tail;                                        // B*128 f32
  float* prot = drug + (size_t)B * 128;                      // B*128 f32
  unsigned short* combh = (unsigned short*)(prot + (size_t)B * 128);  // B*1152 bf16
  unsigned short* act1h = combh + (size_t)B * CONCAT_P;      // B*512 bf16
  float* act2 = (float*)(act1h + (size_t)B * 512);           // B*256 f32

  const int* srcIdx = ei;
  const int* dstIdx = ei + E;

  // ---- CSR build + degree ----
  hipMemsetAsync(rs, 0, ((size_t)N + 1) * sizeof(int), stream);
  k_count<<<(E + 255) / 256, 256, 0, stream>>>(dstIdx, rs, E);
  k_disk<<<(N + 255) / 256, 256, 0, stream>>>(rs, dis, N);
  int NB = (N + 1023) / 1024;
  k_scan_p1<<<NB, 256, 0, stream>>>(rs, part, N);
  k_scan_p2<<<1, 1024, 0, stream>>>(part, NB);
  k_scan_p3<<<NB, 256, 0, stream>>>(rs, part, N);
  k_scatter<<<(E + 255) / 256, 256, 0, stream>>>(srcIdx, dstIdx, rs, csr, E);

  // ---- GCN layers ----
  int mmBlocks = (N + 63) / 64;
  int gatherBlocks = (N + 3) / 4;
  k_mm<30, false><<<mmBlocks, 256, 0, stream>>>(drug_x, W1, nullptr, dis, M, N);
  k_gather<<<gatherBlocks, 256, 0, stream>>>(rs, csr, M, AGG, N);
  k_mm<64, true><<<mmBlocks, 256, 0, stream>>>(AGG, W2, b1, dis, M, N);
  k_gather<<<gatherBlocks, 256, 0, stream>>>(rs, csr, M, AGG, N);
  k_mm<64, true><<<mmBlocks, 256, 0, stream>>>(AGG, W3, b2, dis, M, N);
  k_gather<<<gatherBlocks, 256, 0, stream>>>(rs, csr, M, AGG, N);

  // ---- mean pool (fused final relu) ----
  hipMemsetAsync(sums, 0, ((size_t)B * 64 + B) * sizeof(float), stream);
  int poolWaves = (N + 7) / 8;
  k_pool8<<<(poolWaves + 3) / 4, 256, 0, stream>>>(AGG, dis, b3, batch, sums, cntf, N);

  // ---- dense tail ----
  k_drugfc<<<B, 128, 0, stream>>>(sums, cntf, Wd, bd, drug, B);
  // protein fc: MFMA GEMM, A=f32 [B x 979], W [979 x 128]
  k_gemm_relu<false, float><<<dim3(B / 128, 1), 256, 0, stream>>>(
      protein_x, Wp, bp, prot, 128, 979, 979, (979 + 31) / 32);
  k_concat_ln<<<B, 256, 0, stream>>>(drug, prot, fpp, combh, B);
  // fc1: A=bf16 [B x 1152 padded], W [1137 x 512]
  k_gemm_relu<true, unsigned short><<<dim3(B / 128, 4), 256, 0, stream>>>(
      combh, Wf1, bf1, act1h, 512, CONCAT_F, CONCAT_P, CONCAT_P / 32);
  // fc2: A=bf16 [B x 512], W [512 x 256]
  k_gemm_relu<true, float><<<dim3(B / 128, 2), 256, 0, stream>>>(
      act1h, Wf2, bf2, act2, 256, 512, 512, 512 / 32);
  k_fc3<<<(B + 3) / 4, 256, 0, stream>>>(act2, Wf3, bf3, out, B);
}

// Round 6
// 1266.149 us; speedup vs baseline: 3.1634x; 1.4372x over previous
//
#include <hip/hip_runtime.h>
#include <hip/hip_bf16.h>

#define CONCAT_F 1137
#define CONCAT_P 1152  // padded to multiple of 32 for bf16 MFMA GEMM
#define PROT_K 979
#define PROT_P 992     // 979 padded to 31*32

typedef __attribute__((ext_vector_type(8))) short bf16x8;
typedef __attribute__((ext_vector_type(4))) float f32x4;

static __device__ __forceinline__ float bfu2f(unsigned short u) {
  return __uint_as_float(((unsigned)u) << 16);
}
static __device__ __forceinline__ unsigned short f2bfu(float v) {
  __hip_bfloat16 t = __float2bfloat16(v);
  unsigned short u;
  __builtin_memcpy(&u, &t, 2);
  return u;
}

// ================= CSR build =================
__global__ void k_count(const int* __restrict__ dst, int* __restrict__ rs, int E) {
  int e = blockIdx.x * blockDim.x + threadIdx.x;
  if (e < E) atomicAdd(&rs[dst[e]], 1);
}

__global__ void k_disk(const int* __restrict__ cnt, float* __restrict__ dis, int n) {
  int i = blockIdx.x * blockDim.x + threadIdx.x;
  if (i < n) dis[i] = rsqrtf(1.0f + (float)cnt[i]);  // self-loop included
}

__global__ void k_scan_p1(const int* __restrict__ cnt, int* __restrict__ part, int n) {
  __shared__ int red[256];
  int tid = threadIdx.x;
  long base = (long)blockIdx.x * 1024 + tid * 4;
  int s = 0;
#pragma unroll
  for (int i = 0; i < 4; ++i) {
    long j = base + i;
    if (j < n) s += cnt[j];
  }
  red[tid] = s;
  __syncthreads();
  for (int off = 128; off; off >>= 1) {
    if (tid < off) red[tid] += red[tid + off];
    __syncthreads();
  }
  if (tid == 0) part[blockIdx.x] = red[0];
}

__global__ void k_scan_p2(int* __restrict__ part, int nb) {
  __shared__ int a[1024], b_[1024];
  int t = threadIdx.x;
  a[t] = (t < nb) ? part[t] : 0;
  __syncthreads();
  int* s = a;
  int* d = b_;
  for (int off = 1; off < 1024; off <<= 1) {
    d[t] = s[t] + ((t >= off) ? s[t - off] : 0);
    __syncthreads();
    int* tmp = s;
    s = d;
    d = tmp;
  }
  if (t < nb) part[t] = (t == 0) ? 0 : s[t - 1];  // exclusive
}

__global__ void k_scan_p3(int* __restrict__ rs, const int* __restrict__ part, int n) {
  __shared__ int a[256], b_[256];
  int tid = threadIdx.x;
  long base = (long)blockIdx.x * 1024 + tid * 4;
  int v[4];
#pragma unroll
  for (int i = 0; i < 4; ++i) {
    long j = base + i;
    v[i] = (j < n) ? rs[j] : 0;
  }
  a[tid] = v[0] + v[1] + v[2] + v[3];
  __syncthreads();
  int* s = a;
  int* d = b_;
  for (int off = 1; off < 256; off <<= 1) {
    d[tid] = s[tid] + ((tid >= off) ? s[tid - off] : 0);
    __syncthreads();
    int* t2 = s;
    s = d;
    d = t2;
  }
  int run = part[blockIdx.x] + ((tid == 0) ? 0 : s[tid - 1]);
#pragma unroll
  for (int i = 0; i < 4; ++i) {
    long j = base + i;
    if (j < n) {
      rs[j] = run;
      run += v[i];
    }
  }
}

// scatter with rowStart-shift trick: after this, rs[d] == exclusive_end(d)
__global__ void k_scatter(const int* __restrict__ src, const int* __restrict__ dst,
                          int* __restrict__ rs, int* __restrict__ csr, int E) {
  int e = blockIdx.x * blockDim.x + threadIdx.x;
  if (e < E) {
    int pos = atomicAdd(&rs[dst[e]], 1);
    csr[pos] = src[e];
  }
}

// ================= GCN matmul: M = dis*(act(X)@W), bf16 out =================
template <int K, bool ACT>
__global__ __launch_bounds__(256) void k_mm(const void* __restrict__ Xv,
                                            const float* __restrict__ W,
                                            const float* __restrict__ bprev,
                                            const float* __restrict__ dis,
                                            unsigned short* __restrict__ M, int n) {
  __shared__ __align__(16) float hT[K][68];
  __shared__ __align__(16) float Ws[K * 64];
  __shared__ float disS[64];
  int tid = threadIdx.x;
  int rb = blockIdx.x * 64;
  for (int j = tid; j < K * 16; j += 256) ((float4*)Ws)[j] = ((const float4*)W)[j];
  if (tid < 64) disS[tid] = (rb + tid < n) ? dis[rb + tid] : 0.0f;
  __syncthreads();
  if constexpr (ACT) {
    const unsigned short* X = (const unsigned short*)Xv;
    int k = tid & 63;
    float bk = bprev[k];
#pragma unroll
    for (int r = tid >> 6; r < 64; r += 4) {
      float h = 0.0f;
      if (rb + r < n) {
        float raw = bfu2f(X[(long)(rb + r) * 64 + k]);
        h = fmaxf(fmaf(raw, disS[r], bk), 0.0f);
      }
      hT[k][r] = h;
    }
  } else {
    const float* X = (const float*)Xv;
    for (int idx = tid; idx < 64 * K; idx += 256) {
      int r = idx / K, k = idx - r * K;
      hT[k][r] = (rb + r < n) ? X[(long)(rb + r) * K + k] : 0.0f;
    }
  }
  __syncthreads();
  int rt = (tid & 15) * 4;
  int ct = (tid >> 4) * 4;
  float acc[4][4] = {};
#pragma unroll 5
  for (int k = 0; k < K; ++k) {
    float4 xr = *(const float4*)&hT[k][rt];
    float4 wr = *(const float4*)&Ws[k * 64 + ct];
    float xa[4] = {xr.x, xr.y, xr.z, xr.w};
    float wa[4] = {wr.x, wr.y, wr.z, wr.w};
#pragma unroll
    for (int i = 0; i < 4; ++i)
#pragma unroll
      for (int j = 0; j < 4; ++j) acc[i][j] = fmaf(xa[i], wa[j], acc[i][j]);
  }
#pragma unroll
  for (int i = 0; i < 4; ++i) {
    int row = rb + rt + i;
    if (row >= n) break;
    float dv = disS[rt + i];
    ushort4 pk;
    pk.x = f2bfu(acc[i][0] * dv);
    pk.y = f2bfu(acc[i][1] * dv);
    pk.z = f2bfu(acc[i][2] * dv);
    pk.w = f2bfu(acc[i][3] * dv);
    *(ushort4*)&M[(long)row * 64 + ct] = pk;
  }
}

// ================= gather: AGG[d] = M[d] + sum_{s in csr[d]} M[s] ===========
__global__ void k_gather(const int* __restrict__ rs, const int* __restrict__ csr,
                         const unsigned short* __restrict__ M,
                         unsigned short* __restrict__ AGG, int n) {
  int w = (int)((blockIdx.x * (long)blockDim.x + threadIdx.x) >> 6);
  int lane = threadIdx.x & 63;
  if (w >= n) return;
  int start = (w == 0) ? 0 : rs[w - 1];
  int end = rs[w];
  float a0 = bfu2f(M[(long)w * 64 + lane]);  // self loop
  float a1 = 0.0f;
  int j = start;
  for (; j + 1 < end; j += 2) {
    int s0 = csr[j], s1 = csr[j + 1];
    a0 += bfu2f(M[(long)s0 * 64 + lane]);
    a1 += bfu2f(M[(long)s1 * 64 + lane]);
  }
  if (j < end) a0 += bfu2f(M[(long)csr[j] * 64 + lane]);
  AGG[(long)w * 64 + lane] = f2bfu(a0 + a1);
}

// ============ mean pool (sorted batch) with fused relu(x*dis+b3) ============
__global__ void k_pool8(const unsigned short* __restrict__ H, const float* __restrict__ dis,
                        const float* __restrict__ b3, const int* __restrict__ batch,
                        float* __restrict__ sums, float* __restrict__ cntf, int n) {
  int w = (int)((blockIdx.x * (long)blockDim.x + threadIdx.x) >> 6);
  int lane = threadIdx.x & 63;
  int r0 = w * 8;
  if (r0 >= n) return;
  float bl = b3[lane];
  int cur = batch[r0];
  float acc = fmaxf(fmaf(bfu2f(H[(long)r0 * 64 + lane]), dis[r0], bl), 0.0f);
  float c = 1.0f;
  for (int i = 1; i < 8; ++i) {
    int r = r0 + i;
    if (r >= n) break;
    int b = batch[r];
    float v = fmaxf(fmaf(bfu2f(H[(long)r * 64 + lane]), dis[r], bl), 0.0f);
    if (b == cur) {
      acc += v;
      c += 1.0f;
    } else {
      unsafeAtomicAdd(&sums[(long)cur * 64 + lane], acc);
      if (lane == 0) unsafeAtomicAdd(&cntf[cur], c);
      cur = b;
      acc = v;
      c = 1.0f;
    }
  }
  unsafeAtomicAdd(&sums[(long)cur * 64 + lane], acc);
  if (lane == 0) unsafeAtomicAdd(&cntf[cur], c);
}

// ================= drug fc: relu((sums/cnt) @ Wd + bd), 64 -> 128 ===========
__global__ void k_drugfc(const float* __restrict__ sums, const float* __restrict__ cnt,
                         const float* __restrict__ W, const float* __restrict__ b,
                         float* __restrict__ out, int B) {
  __shared__ float ps[64];
  int row = blockIdx.x;
  int tid = threadIdx.x;
  float inv = 1.0f / fmaxf(cnt[row], 1.0f);
  if (tid < 64) ps[tid] = sums[(long)row * 64 + tid] * inv;
  __syncthreads();
  float acc = b[tid];
#pragma unroll 8
  for (int k = 0; k < 64; ++k) acc = fmaf(ps[k], W[k * 128 + tid], acc);
  out[(long)row * 128 + tid] = fmaxf(acc, 0.0f);
}

// ============ f32 [M x Kin] -> bf16 [M x ldout], zero-padded cols ===========
__global__ void k_cvt_bf16(const float* __restrict__ X, unsigned short* __restrict__ Y,
                           int Kin, int ldout) {
  int row = blockIdx.x;
  const float* xr = X + (size_t)row * Kin;
  unsigned short* yr = Y + (size_t)row * ldout;
  for (int j = threadIdx.x; j < ldout; j += 256)
    yr[j] = (j < Kin) ? f2bfu(xr[j]) : 0;
}

// ===== bf16 MFMA GEMM, 64x128 tile, BK=32, reg-prefetch double-buffer ======
// A: [M x lda] bf16 (lda = 32*nsteps, zero-padded); W: [K x N] f32 (row-guard);
// grid (M/64, N/128, KS). SPLIT: write raw partial to C + z*M*N (f32).
// else: C = relu(A@W + bias) as OT. One barrier per K-step.
template <bool SPLIT, typename OT>
__global__ __launch_bounds__(256, 3) void k_gemm2(
    const unsigned short* __restrict__ A, const float* __restrict__ W,
    const float* __restrict__ bias, OT* __restrict__ C,
    int Mrows, int N, int K, int lda, int nsteps, int chunkSteps) {
  __shared__ __align__(16) unsigned short As[2][64 * 32];
  __shared__ __align__(16) unsigned short Bs[2][128 * 32];
  const int tid = threadIdx.x;
  const int lane = tid & 63;
  const int wid = tid >> 6;
  const int bm = blockIdx.x * 64;
  const int bn = blockIdx.y * 128;
  const int kb = lane >> 4, fr = lane & 15;
  const int ss0 = blockIdx.z * chunkSteps;
  const int ss1 = min(nsteps, ss0 + chunkSteps);

  f32x4 acc[8];
#pragma unroll
  for (int j = 0; j < 8; ++j) acc[j] = f32x4{0.f, 0.f, 0.f, 0.f};

  // read-side swizzled byte offsets
  const int ar = wid * 16 + fr;
  const int aOff = (ar * 64 + kb * 16) ^ ((ar & 7) << 4);
  int bOff[8];
#pragma unroll
  for (int ni = 0; ni < 8; ++ni) {
    int nr = ni * 16 + fr;
    bOff[ni] = (nr * 64 + kb * 16) ^ ((nr & 7) << 4);
  }
  // write-side: A 1 chunk/thread, B 2 chunks/thread
  const int arow = tid >> 2, ac = tid & 3;
  const int aW = (arow * 64 + ac * 16) ^ ((arow & 7) << 4);
  const int bn_ = tid & 127, bk0 = (tid >> 7) * 2;
  int bW[2];
#pragma unroll
  for (int p = 0; p < 2; ++p) {
    int kbb = bk0 + p;
    bW[p] = (bn_ * 64 + kbb * 16) ^ ((bn_ & 7) << 4);
  }

  bf16x8 pa;
  float pb[2][8];
  const unsigned short* aptr = A + (size_t)(bm + arow) * lda + ac * 8;

#define LOAD_STEP(S)                                              \
  {                                                               \
    int k0 = (S) * 32;                                            \
    pa = *(const bf16x8*)(aptr + k0);                             \
    _Pragma("unroll") for (int p = 0; p < 2; ++p) {               \
      _Pragma("unroll") for (int i = 0; i < 8; ++i) {             \
        int gk = k0 + (bk0 + p) * 8 + i;                          \
        pb[p][i] = (gk < K) ? W[(size_t)gk * N + bn + bn_] : 0.f; \
      }                                                           \
    }                                                             \
  }
#define STORE_STEP(BUF)                                           \
  {                                                               \
    *(bf16x8*)((char*)As[BUF] + aW) = pa;                         \
    _Pragma("unroll") for (int p = 0; p < 2; ++p) {               \
      bf16x8 v;                                                   \
      _Pragma("unroll") for (int i = 0; i < 8; ++i)               \
          v[i] = (short)f2bfu(pb[p][i]);                          \
      *(bf16x8*)((char*)Bs[BUF] + bW[p]) = v;                     \
    }                                                             \
  }

  LOAD_STEP(ss0);
  STORE_STEP(0);
  __syncthreads();
  int cur = 0;
  for (int s = ss0; s < ss1; ++s) {
    bool more = (s + 1 < ss1);
    if (more) LOAD_STEP(s + 1);
    bf16x8 a0 = *(const bf16x8*)((char*)As[cur] + aOff);
#pragma unroll
    for (int ni = 0; ni < 8; ++ni) {
      bf16x8 b = *(const bf16x8*)((char*)Bs[cur] + bOff[ni]);
      acc[ni] = __builtin_amdgcn_mfma_f32_16x16x32_bf16(a0, b, acc[ni], 0, 0, 0);
    }
    if (more) {
      STORE_STEP(cur ^ 1);  // other waves read buf[cur]; prev reads of cur^1 fenced
      __syncthreads();
      cur ^= 1;
    }
  }
  // epilogue: C/D layout col=fr, row=kb*4+r within each 16x16 frag
  if constexpr (SPLIT) {
    float* Cz = (float*)C + (size_t)blockIdx.z * Mrows * N;
#pragma unroll
    for (int ni = 0; ni < 8; ++ni)
#pragma unroll
      for (int r = 0; r < 4; ++r) {
        int row = bm + wid * 16 + kb * 4 + r;
        int col = bn + ni * 16 + fr;
        Cz[(size_t)row * N + col] = acc[ni][r];
      }
  } else {
    float bv[8];
#pragma unroll
    for (int ni = 0; ni < 8; ++ni) bv[ni] = bias[bn + ni * 16 + fr];
#pragma unroll
    for (int ni = 0; ni < 8; ++ni)
#pragma unroll
      for (int r = 0; r < 4; ++r) {
        int row = bm + wid * 16 + kb * 4 + r;
        int col = bn + ni * 16 + fr;
        float x = fmaxf(acc[ni][r] + bv[ni], 0.f);
        if constexpr (__hip_internal::is_same<OT, float>::value) {
          C[(size_t)row * N + col] = x;
        } else {
          C[(size_t)row * N + col] = f2bfu(x);
        }
      }
  }
#undef LOAD_STEP
#undef STORE_STEP
}

// ---- concat + LayerNorm; prot = relu(sum of 4 K-split partials + bp) -------
__global__ void k_concat_ln(const float* __restrict__ drug, const float* __restrict__ protP,
                            const float* __restrict__ bp, const float* __restrict__ fpp,
                            unsigned short* __restrict__ comb, int B) {
  __shared__ float buf[CONCAT_F];
  __shared__ float rs[4], rs2[4];
  int row = blockIdx.x;
  int tid = threadIdx.x;
  const size_t MN = (size_t)B * 128;
  float s = 0.0f, s2 = 0.0f;
  for (int j = tid; j < CONCAT_F; j += 256) {
    float v;
    if (j < 128) {
      v = drug[(long)row * 128 + j];
    } else if (j < 256) {
      int c = j - 128;
      size_t o = (size_t)row * 128 + c;
      float acc = protP[o] + protP[MN + o] + protP[2 * MN + o] + protP[3 * MN + o];
      v = fmaxf(acc + bp[c], 0.0f);
    } else {
      v = fpp[(long)row * 881 + (j - 256)];
    }
    buf[j] = v;
    s += v;
    s2 += v * v;
  }
  for (int o = 32; o; o >>= 1) {
    s += __shfl_down(s, o, 64);
    s2 += __shfl_down(s2, o, 64);
  }
  int lane = tid & 63, wid = tid >> 6;
  if (lane == 0) { rs[wid] = s; rs2[wid] = s2; }
  __syncthreads();
  if (tid == 0) {
    float ts = rs[0] + rs[1] + rs[2] + rs[3];
    float ts2 = rs2[0] + rs2[1] + rs2[2] + rs2[3];
    float mu = ts / (float)CONCAT_F;
    float var = ts2 / (float)CONCAT_F - mu * mu;
    rs[0] = mu;
    rs2[0] = rsqrtf(fmaxf(var, 0.0f) + 1e-5f);
  }
  __syncthreads();
  float mu = rs[0], inv = rs2[0];
  for (int j = tid; j < CONCAT_P; j += 256) {
    unsigned short o = (j < CONCAT_F) ? f2bfu((buf[j] - mu) * inv) : 0;
    comb[(long)row * CONCAT_P + j] = o;
  }
}

// ---------------- fc3: X @ w + b, 256 -> 1 ----------------------------------
__global__ void k_fc3(const float* __restrict__ X, const float* __restrict__ W,
                      const float* __restrict__ bias, float* __restrict__ out, int B) {
  int w = (int)((blockIdx.x * (long)blockDim.x + threadIdx.x) >> 6);
  int lane = threadIdx.x & 63;
  if (w >= B) return;
  float s = 0.0f;
#pragma unroll
  for (int j = 0; j < 4; ++j) s = fmaf(X[(long)w * 256 + lane + j * 64], W[lane + j * 64], s);
  for (int o = 32; o; o >>= 1) s += __shfl_down(s, o, 64);
  if (lane == 0) out[w] = s + bias[0];
}

// ---------------------------------------------------------------------------
extern "C" void kernel_launch(void* const* d_in, const int* in_sizes, int n_in,
                              void* d_out, int out_size, void* d_ws, size_t ws_size,
                              hipStream_t stream) {
  const float* drug_x = (const float*)d_in[0];
  const int* ei = (const int*)d_in[1];
  const int* batch = (const int*)d_in[2];
  const float* protein_x = (const float*)d_in[3];
  const float* fpp = (const float*)d_in[4];
  const float* W1 = (const float*)d_in[5];
  const float* b1 = (const float*)d_in[6];
  const float* W2 = (const float*)d_in[7];
  const float* b2 = (const float*)d_in[8];
  const float* W3 = (const float*)d_in[9];
  const float* b3 = (const float*)d_in[10];
  const float* Wd = (const float*)d_in[11];
  const float* bd = (const float*)d_in[12];
  const float* Wp = (const float*)d_in[13];
  const float* bp = (const float*)d_in[14];
  const float* Wf1 = (const float*)d_in[15];
  const float* bf1 = (const float*)d_in[16];
  const float* Wf2 = (const float*)d_in[17];
  const float* bf2 = (const float*)d_in[18];
  const float* Wf3 = (const float*)d_in[19];
  const float* bf3 = (const float*)d_in[20];
  float* out = (float*)d_out;

  const int N = in_sizes[0] / 30;
  const int E = in_sizes[1] / 2;
  const int B = in_sizes[4] / 881;

  // ---- GCN-phase workspace (4-byte words) ----
  int* rs = (int*)d_ws;
  float* dis = (float*)d_ws + ((size_t)N + 1);
  int* csr = (int*)d_ws + (2 * (size_t)N + 1);
  size_t oM = 2 * (size_t)N + 2 + (size_t)E;
  unsigned short* M = (unsigned short*)((float*)d_ws + oM);
  unsigned short* AGG = M + (size_t)N * 64;
  float* sums = (float*)d_ws + (oM + 64 * (size_t)N);
  float* cntf = sums + (size_t)B * 64;
  int* part = (int*)(cntf + B);
  // protein bf16 (disjoint, lives whole call): after part
  unsigned short* protbh = (unsigned short*)(part + 1024);  // B*PROT_P bf16
  // ---- dense-tail aliases at offset 0 (GCN buffers dead by then) ----
  float* tail = (float*)d_ws;
  float* drug = tail;                                        // B*128 f32
  float* protP = drug + (size_t)B * 128;                     // 4*B*128 f32 partials
  unsigned short* combh = (unsigned short*)(protP + 4 * (size_t)B * 128);  // B*1152 bf16
  unsigned short* act1h = combh + (size_t)B * CONCAT_P;      // B*512 bf16
  float* act2 = (float*)(act1h + (size_t)B * 512);           // B*256 f32

  const int* srcIdx = ei;
  const int* dstIdx = ei + E;

  // ---- protein f32 -> bf16 (input-only dependency; fully disjoint buffer) --
  k_cvt_bf16<<<B, 256, 0, stream>>>(protein_x, protbh, PROT_K, PROT_P);

  // ---- CSR build + degree ----
  hipMemsetAsync(rs, 0, ((size_t)N + 1) * sizeof(int), stream);
  k_count<<<(E + 255) / 256, 256, 0, stream>>>(dstIdx, rs, E);
  k_disk<<<(N + 255) / 256, 256, 0, stream>>>(rs, dis, N);
  int NB = (N + 1023) / 1024;
  k_scan_p1<<<NB, 256, 0, stream>>>(rs, part, N);
  k_scan_p2<<<1, 1024, 0, stream>>>(part, NB);
  k_scan_p3<<<NB, 256, 0, stream>>>(rs, part, N);
  k_scatter<<<(E + 255) / 256, 256, 0, stream>>>(srcIdx, dstIdx, rs, csr, E);

  // ---- GCN layers ----
  int mmBlocks = (N + 63) / 64;
  int gatherBlocks = (N + 3) / 4;
  k_mm<30, false><<<mmBlocks, 256, 0, stream>>>(drug_x, W1, nullptr, dis, M, N);
  k_gather<<<gatherBlocks, 256, 0, stream>>>(rs, csr, M, AGG, N);
  k_mm<64, true><<<mmBlocks, 256, 0, stream>>>(AGG, W2, b1, dis, M, N);
  k_gather<<<gatherBlocks, 256, 0, stream>>>(rs, csr, M, AGG, N);
  k_mm<64, true><<<mmBlocks, 256, 0, stream>>>(AGG, W3, b2, dis, M, N);
  k_gather<<<gatherBlocks, 256, 0, stream>>>(rs, csr, M, AGG, N);

  // ---- mean pool (fused final relu) ----
  hipMemsetAsync(sums, 0, ((size_t)B * 64 + B) * sizeof(float), stream);
  int poolWaves = (N + 7) / 8;
  k_pool8<<<(poolWaves + 3) / 4, 256, 0, stream>>>(AGG, dis, b3, batch, sums, cntf, N);

  // ---- dense tail ----
  k_drugfc<<<B, 128, 0, stream>>>(sums, cntf, Wd, bd, drug, B);
  // protein fc: K-split x4 into partials (31 steps -> 8,8,8,7)
  k_gemm2<true, float><<<dim3(B / 64, 1, 4), 256, 0, stream>>>(
      protbh, Wp, nullptr, protP, B, 128, PROT_K, PROT_P, 31, 8);
  k_concat_ln<<<B, 256, 0, stream>>>(drug, protP, bp, fpp, combh, B);
  // fc1: 1152 -> 512
  k_gemm2<false, unsigned short><<<dim3(B / 64, 4, 1), 256, 0, stream>>>(
      combh, Wf1, bf1, act1h, B, 512, CONCAT_F, CONCAT_P, 36, 36);
  // fc2: 512 -> 256
  k_gemm2<false, float><<<dim3(B / 64, 2, 1), 256, 0, stream>>>(
      act1h, Wf2, bf2, act2, B, 256, 512, 512, 16, 16);
  k_fc3<<<(B + 3) / 4, 256, 0, stream>>>(act2, Wf3, bf3, out, B);
}

// Round 7
// 902.800 us; speedup vs baseline: 4.4366x; 1.4025x over previous
//
#include <hip/hip_runtime.h>
#include <hip/hip_bf16.h>

#define CONCAT_F 1137
#define CONCAT_P 1152  // padded to multiple of 32 for bf16 MFMA GEMM
#define PROT_K 979
#define PROT_P 992     // 979 padded to 31*32

typedef __attribute__((ext_vector_type(8))) short bf16x8;
typedef __attribute__((ext_vector_type(4))) float f32x4;

static __device__ __forceinline__ float bfu2f(unsigned short u) {
  return __uint_as_float(((unsigned)u) << 16);
}
static __device__ __forceinline__ unsigned short f2bfu(float v) {
  __hip_bfloat16 t = __float2bfloat16(v);
  unsigned short u;
  __builtin_memcpy(&u, &t, 2);
  return u;
}

// ================= CSR build =================
__global__ void k_count(const int* __restrict__ dst, int* __restrict__ rs, int E) {
  int e = blockIdx.x * blockDim.x + threadIdx.x;
  if (e < E) atomicAdd(&rs[dst[e]], 1);
}

__global__ void k_disk(const int* __restrict__ cnt, float* __restrict__ dis, int n) {
  int i = blockIdx.x * blockDim.x + threadIdx.x;
  if (i < n) dis[i] = rsqrtf(1.0f + (float)cnt[i]);  // self-loop included
}

__global__ void k_scan_p1(const int* __restrict__ cnt, int* __restrict__ part, int n) {
  __shared__ int red[256];
  int tid = threadIdx.x;
  long base = (long)blockIdx.x * 1024 + tid * 4;
  int s = 0;
#pragma unroll
  for (int i = 0; i < 4; ++i) {
    long j = base + i;
    if (j < n) s += cnt[j];
  }
  red[tid] = s;
  __syncthreads();
  for (int off = 128; off; off >>= 1) {
    if (tid < off) red[tid] += red[tid + off];
    __syncthreads();
  }
  if (tid == 0) part[blockIdx.x] = red[0];
}

__global__ void k_scan_p2(int* __restrict__ part, int nb) {
  __shared__ int a[1024], b_[1024];
  int t = threadIdx.x;
  a[t] = (t < nb) ? part[t] : 0;
  __syncthreads();
  int* s = a;
  int* d = b_;
  for (int off = 1; off < 1024; off <<= 1) {
    d[t] = s[t] + ((t >= off) ? s[t - off] : 0);
    __syncthreads();
    int* tmp = s;
    s = d;
    d = tmp;
  }
  if (t < nb) part[t] = (t == 0) ? 0 : s[t - 1];  // exclusive
}

__global__ void k_scan_p3(int* __restrict__ rs, const int* __restrict__ part, int n) {
  __shared__ int a[256], b_[256];
  int tid = threadIdx.x;
  long base = (long)blockIdx.x * 1024 + tid * 4;
  int v[4];
#pragma unroll
  for (int i = 0; i < 4; ++i) {
    long j = base + i;
    v[i] = (j < n) ? rs[j] : 0;
  }
  a[tid] = v[0] + v[1] + v[2] + v[3];
  __syncthreads();
  int* s = a;
  int* d = b_;
  for (int off = 1; off < 256; off <<= 1) {
    d[tid] = s[tid] + ((tid >= off) ? s[tid - off] : 0);
    __syncthreads();
    int* t2 = s;
    s = d;
    d = t2;
  }
  int run = part[blockIdx.x] + ((tid == 0) ? 0 : s[tid - 1]);
#pragma unroll
  for (int i = 0; i < 4; ++i) {
    long j = base + i;
    if (j < n) {
      rs[j] = run;
      run += v[i];
    }
  }
}

// scatter with rowStart-shift trick: after this, rs[d] == exclusive_end(d)
__global__ void k_scatter(const int* __restrict__ src, const int* __restrict__ dst,
                          int* __restrict__ rs, int* __restrict__ csr, int E) {
  int e = blockIdx.x * blockDim.x + threadIdx.x;
  if (e < E) {
    int pos = atomicAdd(&rs[dst[e]], 1);
    csr[pos] = src[e];
  }
}

// ====== GCN layer-1 matmul: M = dis*(X@W), f32 in, bf16 out (K=30) =========
template <int K, bool ACT>
__global__ __launch_bounds__(256) void k_mm(const void* __restrict__ Xv,
                                            const float* __restrict__ W,
                                            const float* __restrict__ bprev,
                                            const float* __restrict__ dis,
                                            unsigned short* __restrict__ M, int n) {
  __shared__ __align__(16) float hT[K][68];
  __shared__ __align__(16) float Ws[K * 64];
  __shared__ float disS[64];
  int tid = threadIdx.x;
  int rb = blockIdx.x * 64;
  for (int j = tid; j < K * 16; j += 256) ((float4*)Ws)[j] = ((const float4*)W)[j];
  if (tid < 64) disS[tid] = (rb + tid < n) ? dis[rb + tid] : 0.0f;
  __syncthreads();
  if constexpr (ACT) {
    const unsigned short* X = (const unsigned short*)Xv;
    int k = tid & 63;
    float bk = bprev[k];
#pragma unroll
    for (int r = tid >> 6; r < 64; r += 4) {
      float h = 0.0f;
      if (rb + r < n) {
        float raw = bfu2f(X[(long)(rb + r) * 64 + k]);
        h = fmaxf(fmaf(raw, disS[r], bk), 0.0f);
      }
      hT[k][r] = h;
    }
  } else {
    const float* X = (const float*)Xv;
    for (int idx = tid; idx < 64 * K; idx += 256) {
      int r = idx / K, k = idx - r * K;
      hT[k][r] = (rb + r < n) ? X[(long)(rb + r) * K + k] : 0.0f;
    }
  }
  __syncthreads();
  int rt = (tid & 15) * 4;
  int ct = (tid >> 4) * 4;
  float acc[4][4] = {};
#pragma unroll 5
  for (int k = 0; k < K; ++k) {
    float4 xr = *(const float4*)&hT[k][rt];
    float4 wr = *(const float4*)&Ws[k * 64 + ct];
    float xa[4] = {xr.x, xr.y, xr.z, xr.w};
    float wa[4] = {wr.x, wr.y, wr.z, wr.w};
#pragma unroll
    for (int i = 0; i < 4; ++i)
#pragma unroll
      for (int j = 0; j < 4; ++j) acc[i][j] = fmaf(xa[i], wa[j], acc[i][j]);
  }
#pragma unroll
  for (int i = 0; i < 4; ++i) {
    int row = rb + rt + i;
    if (row >= n) break;
    float dv = disS[rt + i];
    ushort4 pk;
    pk.x = f2bfu(acc[i][0] * dv);
    pk.y = f2bfu(acc[i][1] * dv);
    pk.z = f2bfu(acc[i][2] * dv);
    pk.w = f2bfu(acc[i][3] * dv);
    *(ushort4*)&M[(long)row * 64 + ct] = pk;
  }
}

// ===== GCN layers 2/3 matmul via MFMA: M = dis*(H@W), 64x64 tile, K=64 =====
__global__ __launch_bounds__(256) void k_mmg(const unsigned short* __restrict__ H,
                                             const float* __restrict__ W,
                                             const float* __restrict__ dis,
                                             unsigned short* __restrict__ M, int n) {
  __shared__ __align__(16) unsigned short As[64 * 64];  // row stride 128B, swizzled
  __shared__ __align__(16) unsigned short Bt[64 * 64];  // [n][k], swizzled
  const int tid = threadIdx.x;
  const int bm = blockIdx.x * 64;
  // stage A: 64 rows x 128B; 4 threads/row, 2x16B chunks each
  {
    int row = tid >> 2;
    const unsigned short* src = H + (size_t)(bm + row) * 64;
    bool ok = (bm + row) < n;
#pragma unroll
    for (int p = 0; p < 2; ++p) {
      int c = (tid & 3) + p * 4;
      bf16x8 v;
      if (ok) v = *(const bf16x8*)(src + c * 8);
      else v = bf16x8{0, 0, 0, 0, 0, 0, 0, 0};
      int off = (row * 128 + c * 16) ^ ((row & 7) << 4);
      *(bf16x8*)((char*)As + off) = v;
    }
  }
  // stage Bt[n][k] = W[k][n] as bf16; thread: n = tid&63, k0 = (tid>>6)*16
  {
    int nn = tid & 63, k0 = (tid >> 6) * 16;
    bf16x8 v0, v1;
#pragma unroll
    for (int i = 0; i < 8; ++i) v0[i] = (short)f2bfu(W[(size_t)(k0 + i) * 64 + nn]);
#pragma unroll
    for (int i = 0; i < 8; ++i) v1[i] = (short)f2bfu(W[(size_t)(k0 + 8 + i) * 64 + nn]);
    int off0 = (nn * 128 + k0 * 2) ^ ((nn & 7) << 4);
    int off1 = (nn * 128 + (k0 + 8) * 2) ^ ((nn & 7) << 4);
    *(bf16x8*)((char*)Bt + off0) = v0;
    *(bf16x8*)((char*)Bt + off1) = v1;
  }
  __syncthreads();
  const int lane = tid & 63, wid = tid >> 6;
  const int kb = lane >> 4, fr = lane & 15;
  f32x4 acc[4];
#pragma unroll
  for (int i = 0; i < 4; ++i) acc[i] = f32x4{0.f, 0.f, 0.f, 0.f};
  const int ar = wid * 16 + fr;
#pragma unroll
  for (int kc = 0; kc < 2; ++kc) {
    int aoff = (ar * 128 + kc * 64 + kb * 16) ^ ((ar & 7) << 4);
    bf16x8 a = *(const bf16x8*)((char*)As + aoff);
#pragma unroll
    for (int ni = 0; ni < 4; ++ni) {
      int nr = ni * 16 + fr;
      int boff = (nr * 128 + kc * 64 + kb * 16) ^ ((nr & 7) << 4);
      bf16x8 b = *(const bf16x8*)((char*)Bt + boff);
      acc[ni] = __builtin_amdgcn_mfma_f32_16x16x32_bf16(a, b, acc[ni], 0, 0, 0);
    }
  }
  // epilogue: C/D frag row = kb*4+r, col = ni*16+fr; scale by dis[row]
#pragma unroll
  for (int r = 0; r < 4; ++r) {
    int row = bm + wid * 16 + kb * 4 + r;
    if (row < n) {
      float dv = dis[row];
#pragma unroll
      for (int ni = 0; ni < 4; ++ni)
        M[(size_t)row * 64 + ni * 16 + fr] = f2bfu(acc[ni][r] * dv);
    }
  }
}

// == gather+act: H[d] = relu((M[d] + sum_{s in csr[d]} M[s]) * dis[d] + b) ==
// 4 nodes per wave: 16 lanes x uint2 (8B) cover a 128B row; 2-edge unroll.
__global__ void k_gather_act(const int* __restrict__ rs, const int* __restrict__ csr,
                             const unsigned short* __restrict__ M,
                             const float* __restrict__ dis, const float* __restrict__ bias,
                             unsigned short* __restrict__ H, int n) {
  int w = (int)((blockIdx.x * (long)blockDim.x + threadIdx.x) >> 6);
  int lane = threadIdx.x & 63;
  int grp = lane >> 4, l16 = lane & 15;
  int node = w * 4 + grp;
  bool act = node < n;
  int start = 0, end = 0;
  if (act) {
    start = (node == 0) ? 0 : rs[node - 1];
    end = rs[node];
  }
  float a0 = 0.f, a1 = 0.f, a2 = 0.f, a3 = 0.f;
  float c0 = 0.f, c1 = 0.f, c2 = 0.f, c3 = 0.f;
  if (act) {
    uint2 v = *(const uint2*)(M + (size_t)node * 64 + l16 * 4);  // self loop
    a0 = bfu2f(v.x & 0xffffu);
    a1 = bfu2f(v.x >> 16);
    a2 = bfu2f(v.y & 0xffffu);
    a3 = bfu2f(v.y >> 16);
  }
  int j = start;
  for (; j + 1 < end; j += 2) {
    int s0 = csr[j], s1 = csr[j + 1];
    uint2 u = *(const uint2*)(M + (size_t)s0 * 64 + l16 * 4);
    uint2 v = *(const uint2*)(M + (size_t)s1 * 64 + l16 * 4);
    a0 += bfu2f(u.x & 0xffffu);
    a1 += bfu2f(u.x >> 16);
    a2 += bfu2f(u.y & 0xffffu);
    a3 += bfu2f(u.y >> 16);
    c0 += bfu2f(v.x & 0xffffu);
    c1 += bfu2f(v.x >> 16);
    c2 += bfu2f(v.y & 0xffffu);
    c3 += bfu2f(v.y >> 16);
  }
  if (j < end) {
    uint2 u = *(const uint2*)(M + (size_t)csr[j] * 64 + l16 * 4);
    a0 += bfu2f(u.x & 0xffffu);
    a1 += bfu2f(u.x >> 16);
    a2 += bfu2f(u.y & 0xffffu);
    a3 += bfu2f(u.y >> 16);
  }
  if (act) {
    float dv = dis[node];
    float4 bb = *(const float4*)(bias + l16 * 4);
    ushort4 o;
    o.x = f2bfu(fmaxf(fmaf(a0 + c0, dv, bb.x), 0.f));
    o.y = f2bfu(fmaxf(fmaf(a1 + c1, dv, bb.y), 0.f));
    o.z = f2bfu(fmaxf(fmaf(a2 + c2, dv, bb.z), 0.f));
    o.w = f2bfu(fmaxf(fmaf(a3 + c3, dv, bb.w), 0.f));
    *(ushort4*)(H + (size_t)node * 64 + l16 * 4) = o;
  }
}

// ============ mean pool over sorted batch (H already post-relu) =============
__global__ void k_pool8(const unsigned short* __restrict__ H, const int* __restrict__ batch,
                        float* __restrict__ sums, float* __restrict__ cntf, int n) {
  int w = (int)((blockIdx.x * (long)blockDim.x + threadIdx.x) >> 6);
  int lane = threadIdx.x & 63;
  int r0 = w * 8;
  if (r0 >= n) return;
  int cur = batch[r0];
  float acc = bfu2f(H[(long)r0 * 64 + lane]);
  float c = 1.0f;
  for (int i = 1; i < 8; ++i) {
    int r = r0 + i;
    if (r >= n) break;
    int b = batch[r];
    float v = bfu2f(H[(long)r * 64 + lane]);
    if (b == cur) {
      acc += v;
      c += 1.0f;
    } else {
      unsafeAtomicAdd(&sums[(long)cur * 64 + lane], acc);
      if (lane == 0) unsafeAtomicAdd(&cntf[cur], c);
      cur = b;
      acc = v;
      c = 1.0f;
    }
  }
  unsafeAtomicAdd(&sums[(long)cur * 64 + lane], acc);
  if (lane == 0) unsafeAtomicAdd(&cntf[cur], c);
}

// ================= drug fc: relu((sums/cnt) @ Wd + bd), 64 -> 128 ===========
__global__ void k_drugfc(const float* __restrict__ sums, const float* __restrict__ cnt,
                         const float* __restrict__ W, const float* __restrict__ b,
                         float* __restrict__ out, int B) {
  __shared__ float ps[64];
  int row = blockIdx.x;
  int tid = threadIdx.x;
  float inv = 1.0f / fmaxf(cnt[row], 1.0f);
  if (tid < 64) ps[tid] = sums[(long)row * 64 + tid] * inv;
  __syncthreads();
  float acc = b[tid];
#pragma unroll 8
  for (int k = 0; k < 64; ++k) acc = fmaf(ps[k], W[k * 128 + tid], acc);
  out[(long)row * 128 + tid] = fmaxf(acc, 0.0f);
}

// ============ f32 [M x Kin] -> bf16 [M x ldout], zero-padded cols ===========
__global__ void k_cvt_bf16(const float* __restrict__ X, unsigned short* __restrict__ Y,
                           int Kin, int ldout) {
  int row = blockIdx.x;
  const float* xr = X + (size_t)row * Kin;
  unsigned short* yr = Y + (size_t)row * ldout;
  for (int j = threadIdx.x; j < ldout; j += 256)
    yr[j] = (j < Kin) ? f2bfu(xr[j]) : 0;
}

// ===== bf16 MFMA GEMM, 64x128 tile, BK=32, reg-prefetch double-buffer ======
template <bool SPLIT, typename OT>
__global__ __launch_bounds__(256, 3) void k_gemm2(
    const unsigned short* __restrict__ A, const float* __restrict__ W,
    const float* __restrict__ bias, OT* __restrict__ C,
    int Mrows, int N, int K, int lda, int nsteps, int chunkSteps) {
  __shared__ __align__(16) unsigned short As[2][64 * 32];
  __shared__ __align__(16) unsigned short Bs[2][128 * 32];
  const int tid = threadIdx.x;
  const int lane = tid & 63;
  const int wid = tid >> 6;
  const int bm = blockIdx.x * 64;
  const int bn = blockIdx.y * 128;
  const int kb = lane >> 4, fr = lane & 15;
  const int ss0 = blockIdx.z * chunkSteps;
  const int ss1 = min(nsteps, ss0 + chunkSteps);

  f32x4 acc[8];
#pragma unroll
  for (int j = 0; j < 8; ++j) acc[j] = f32x4{0.f, 0.f, 0.f, 0.f};

  const int ar = wid * 16 + fr;
  const int aOff = (ar * 64 + kb * 16) ^ ((ar & 7) << 4);
  int bOff[8];
#pragma unroll
  for (int ni = 0; ni < 8; ++ni) {
    int nr = ni * 16 + fr;
    bOff[ni] = (nr * 64 + kb * 16) ^ ((nr & 7) << 4);
  }
  const int arow = tid >> 2, ac = tid & 3;
  const int aW = (arow * 64 + ac * 16) ^ ((arow & 7) << 4);
  const int bn_ = tid & 127, bk0 = (tid >> 7) * 2;
  int bW[2];
#pragma unroll
  for (int p = 0; p < 2; ++p) {
    int kbb = bk0 + p;
    bW[p] = (bn_ * 64 + kbb * 16) ^ ((bn_ & 7) << 4);
  }

  bf16x8 pa;
  float pb[2][8];
  const unsigned short* aptr = A + (size_t)(bm + arow) * lda + ac * 8;

#define LOAD_STEP(S)                                              \
  {                                                               \
    int k0 = (S) * 32;                                            \
    pa = *(const bf16x8*)(aptr + k0);                             \
    _Pragma("unroll") for (int p = 0; p < 2; ++p) {               \
      _Pragma("unroll") for (int i = 0; i < 8; ++i) {             \
        int gk = k0 + (bk0 + p) * 8 + i;                          \
        pb[p][i] = (gk < K) ? W[(size_t)gk * N + bn + bn_] : 0.f; \
      }                                                           \
    }                                                             \
  }
#define STORE_STEP(BUF)                                           \
  {                                                               \
    *(bf16x8*)((char*)As[BUF] + aW) = pa;                         \
    _Pragma("unroll") for (int p = 0; p < 2; ++p) {               \
      bf16x8 v;                                                   \
      _Pragma("unroll") for (int i = 0; i < 8; ++i)               \
          v[i] = (short)f2bfu(pb[p][i]);                          \
      *(bf16x8*)((char*)Bs[BUF] + bW[p]) = v;                     \
    }                                                             \
  }

  LOAD_STEP(ss0);
  STORE_STEP(0);
  __syncthreads();
  int cur = 0;
  for (int s = ss0; s < ss1; ++s) {
    bool more = (s + 1 < ss1);
    if (more) LOAD_STEP(s + 1);
    bf16x8 a0 = *(const bf16x8*)((char*)As[cur] + aOff);
#pragma unroll
    for (int ni = 0; ni < 8; ++ni) {
      bf16x8 b = *(const bf16x8*)((char*)Bs[cur] + bOff[ni]);
      acc[ni] = __builtin_amdgcn_mfma_f32_16x16x32_bf16(a0, b, acc[ni], 0, 0, 0);
    }
    if (more) {
      STORE_STEP(cur ^ 1);
      __syncthreads();
      cur ^= 1;
    }
  }
  if constexpr (SPLIT) {
    float* Cz = (float*)C + (size_t)blockIdx.z * Mrows * N;
#pragma unroll
    for (int ni = 0; ni < 8; ++ni)
#pragma unroll
      for (int r = 0; r < 4; ++r) {
        int row = bm + wid * 16 + kb * 4 + r;
        int col = bn + ni * 16 + fr;
        Cz[(size_t)row * N + col] = acc[ni][r];
      }
  } else {
    float bv[8];
#pragma unroll
    for (int ni = 0; ni < 8; ++ni) bv[ni] = bias[bn + ni * 16 + fr];
#pragma unroll
    for (int ni = 0; ni < 8; ++ni)
#pragma unroll
      for (int r = 0; r < 4; ++r) {
        int row = bm + wid * 16 + kb * 4 + r;
        int col = bn + ni * 16 + fr;
        float x = fmaxf(acc[ni][r] + bv[ni], 0.f);
        if constexpr (__hip_internal::is_same<OT, float>::value) {
          C[(size_t)row * N + col] = x;
        } else {
          C[(size_t)row * N + col] = f2bfu(x);
        }
      }
  }
#undef LOAD_STEP
#undef STORE_STEP
}

// ---- concat + LayerNorm; prot = relu(sum of 4 K-split partials + bp) -------
__global__ void k_concat_ln(const float* __restrict__ drug, const float* __restrict__ protP,
                            const float* __restrict__ bp, const float* __restrict__ fpp,
                            unsigned short* __restrict__ comb, int B) {
  __shared__ float buf[CONCAT_F];
  __shared__ float rs[4], rs2[4];
  int row = blockIdx.x;
  int tid = threadIdx.x;
  const size_t MN = (size_t)B * 128;
  float s = 0.0f, s2 = 0.0f;
  for (int j = tid; j < CONCAT_F; j += 256) {
    float v;
    if (j < 128) {
      v = drug[(long)row * 128 + j];
    } else if (j < 256) {
      int c = j - 128;
      size_t o = (size_t)row * 128 + c;
      float acc = protP[o] + protP[MN + o] + protP[2 * MN + o] + protP[3 * MN + o];
      v = fmaxf(acc + bp[c], 0.0f);
    } else {
      v = fpp[(long)row * 881 + (j - 256)];
    }
    buf[j] = v;
    s += v;
    s2 += v * v;
  }
  for (int o = 32; o; o >>= 1) {
    s += __shfl_down(s, o, 64);
    s2 += __shfl_down(s2, o, 64);
  }
  int lane = tid & 63, wid = tid >> 6;
  if (lane == 0) { rs[wid] = s; rs2[wid] = s2; }
  __syncthreads();
  if (tid == 0) {
    float ts = rs[0] + rs[1] + rs[2] + rs[3];
    float ts2 = rs2[0] + rs2[1] + rs2[2] + rs2[3];
    float mu = ts / (float)CONCAT_F;
    float var = ts2 / (float)CONCAT_F - mu * mu;
    rs[0] = mu;
    rs2[0] = rsqrtf(fmaxf(var, 0.0f) + 1e-5f);
  }
  __syncthreads();
  float mu = rs[0], inv = rs2[0];
  for (int j = tid; j < CONCAT_P; j += 256) {
    unsigned short o = (j < CONCAT_F) ? f2bfu((buf[j] - mu) * inv) : 0;
    comb[(long)row * CONCAT_P + j] = o;
  }
}

// ---------------- fc3: X @ w + b, 256 -> 1 ----------------------------------
__global__ void k_fc3(const float* __restrict__ X, const float* __restrict__ W,
                      const float* __restrict__ bias, float* __restrict__ out, int B) {
  int w = (int)((blockIdx.x * (long)blockDim.x + threadIdx.x) >> 6);
  int lane = threadIdx.x & 63;
  if (w >= B) return;
  float s = 0.0f;
#pragma unroll
  for (int j = 0; j < 4; ++j) s = fmaf(X[(long)w * 256 + lane + j * 64], W[lane + j * 64], s);
  for (int o = 32; o; o >>= 1) s += __shfl_down(s, o, 64);
  if (lane == 0) out[w] = s + bias[0];
}

// ---------------------------------------------------------------------------
extern "C" void kernel_launch(void* const* d_in, const int* in_sizes, int n_in,
                              void* d_out, int out_size, void* d_ws, size_t ws_size,
                              hipStream_t stream) {
  const float* drug_x = (const float*)d_in[0];
  const int* ei = (const int*)d_in[1];
  const int* batch = (const int*)d_in[2];
  const float* protein_x = (const float*)d_in[3];
  const float* fpp = (const float*)d_in[4];
  const float* W1 = (const float*)d_in[5];
  const float* b1 = (const float*)d_in[6];
  const float* W2 = (const float*)d_in[7];
  const float* b2 = (const float*)d_in[8];
  const float* W3 = (const float*)d_in[9];
  const float* b3 = (const float*)d_in[10];
  const float* Wd = (const float*)d_in[11];
  const float* bd = (const float*)d_in[12];
  const float* Wp = (const float*)d_in[13];
  const float* bp = (const float*)d_in[14];
  const float* Wf1 = (const float*)d_in[15];
  const float* bf1 = (const float*)d_in[16];
  const float* Wf2 = (const float*)d_in[17];
  const float* bf2 = (const float*)d_in[18];
  const float* Wf3 = (const float*)d_in[19];
  const float* bf3 = (const float*)d_in[20];
  float* out = (float*)d_out;

  const int N = in_sizes[0] / 30;
  const int E = in_sizes[1] / 2;
  const int B = in_sizes[4] / 881;

  // ---- GCN-phase workspace (4-byte words) ----
  int* rs = (int*)d_ws;
  float* dis = (float*)d_ws + ((size_t)N + 1);
  int* csr = (int*)d_ws + (2 * (size_t)N + 1);
  size_t oM = 2 * (size_t)N + 2 + (size_t)E;
  unsigned short* M = (unsigned short*)((float*)d_ws + oM);
  unsigned short* H = M + (size_t)N * 64;
  float* sums = (float*)d_ws + (oM + 64 * (size_t)N);
  float* cntf = sums + (size_t)B * 64;
  int* part = (int*)(cntf + B);
  unsigned short* protbh = (unsigned short*)(part + 1024);  // B*PROT_P bf16
  // ---- dense-tail aliases at offset 0 (GCN buffers dead by then) ----
  float* tail = (float*)d_ws;
  float* drug = tail;                                        // B*128 f32
  float* protP = drug + (size_t)B * 128;                     // 4*B*128 f32 partials
  unsigned short* combh = (unsigned short*)(protP + 4 * (size_t)B * 128);  // B*1152 bf16
  unsigned short* act1h = combh + (size_t)B * CONCAT_P;      // B*512 bf16
  float* act2 = (float*)(act1h + (size_t)B * 512);           // B*256 f32

  const int* srcIdx = ei;
  const int* dstIdx = ei + E;

  // ---- protein f32 -> bf16 ----
  k_cvt_bf16<<<B, 256, 0, stream>>>(protein_x, protbh, PROT_K, PROT_P);

  // ---- CSR build + degree ----
  hipMemsetAsync(rs, 0, ((size_t)N + 1) * sizeof(int), stream);
  k_count<<<(E + 255) / 256, 256, 0, stream>>>(dstIdx, rs, E);
  k_disk<<<(N + 255) / 256, 256, 0, stream>>>(rs, dis, N);
  int NB = (N + 1023) / 1024;
  k_scan_p1<<<NB, 256, 0, stream>>>(rs, part, N);
  k_scan_p2<<<1, 1024, 0, stream>>>(part, NB);
  k_scan_p3<<<NB, 256, 0, stream>>>(rs, part, N);
  k_scatter<<<(E + 255) / 256, 256, 0, stream>>>(srcIdx, dstIdx, rs, csr, E);

  // ---- GCN layers ----
  int mmBlocks = (N + 63) / 64;
  int gWaves = (N + 3) / 4;
  int gBlocks = (gWaves + 3) / 4;
  k_mm<30, false><<<mmBlocks, 256, 0, stream>>>(drug_x, W1, nullptr, dis, M, N);
  k_gather_act<<<gBlocks, 256, 0, stream>>>(rs, csr, M, dis, b1, H, N);
  k_mmg<<<mmBlocks, 256, 0, stream>>>(H, W2, dis, M, N);
  k_gather_act<<<gBlocks, 256, 0, stream>>>(rs, csr, M, dis, b2, H, N);
  k_mmg<<<mmBlocks, 256, 0, stream>>>(H, W3, dis, M, N);
  k_gather_act<<<gBlocks, 256, 0, stream>>>(rs, csr, M, dis, b3, H, N);

  // ---- mean pool ----
  hipMemsetAsync(sums, 0, ((size_t)B * 64 + B) * sizeof(float), stream);
  int poolWaves = (N + 7) / 8;
  k_pool8<<<(poolWaves + 3) / 4, 256, 0, stream>>>(H, batch, sums, cntf, N);

  // ---- dense tail ----
  k_drugfc<<<B, 128, 0, stream>>>(sums, cntf, Wd, bd, drug, B);
  k_gemm2<true, float><<<dim3(B / 64, 1, 4), 256, 0, stream>>>(
      protbh, Wp, nullptr, protP, B, 128, PROT_K, PROT_P, 31, 8);
  k_concat_ln<<<B, 256, 0, stream>>>(drug, protP, bp, fpp, combh, B);
  k_gemm2<false, unsigned short><<<dim3(B / 64, 4, 1), 256, 0, stream>>>(
      combh, Wf1, bf1, act1h, B, 512, CONCAT_F, CONCAT_P, 36, 36);
  k_gemm2<false, float><<<dim3(B / 64, 2, 1), 256, 0, stream>>>(
      act1h, Wf2, bf2, act2, B, 256, 512, 512, 16, 16);
  k_fc3<<<(B + 3) / 4, 256, 0, stream>>>(act2, Wf3, bf3, out, B);
}

// Round 8
// 878.155 us; speedup vs baseline: 4.5611x; 1.0281x over previous
//
#include <hip/hip_runtime.h>
#include <hip/hip_bf16.h>

#define CONCAT_F 1137
#define CONCAT_P 1152  // padded to multiple of 32 for bf16 MFMA GEMM
#define PROT_K 979
#define PROT_P 992     // 979 padded to 31*32

typedef __attribute__((ext_vector_type(8))) short bf16x8;
typedef __attribute__((ext_vector_type(4))) float f32x4;

static __device__ __forceinline__ float bfu2f(unsigned short u) {
  return __uint_as_float(((unsigned)u) << 16);
}
static __device__ __forceinline__ unsigned short f2bfu(float v) {
  __hip_bfloat16 t = __float2bfloat16(v);
  unsigned short u;
  __builtin_memcpy(&u, &t, 2);
  return u;
}

// ================= CSR build =================
__global__ void k_count(const int* __restrict__ dst, int* __restrict__ rs, int E) {
  int e = blockIdx.x * blockDim.x + threadIdx.x;
  if (e < E) atomicAdd(&rs[dst[e]], 1);
}

__global__ void k_disk(const int* __restrict__ cnt, float* __restrict__ dis, int n) {
  int i = blockIdx.x * blockDim.x + threadIdx.x;
  if (i < n) dis[i] = rsqrtf(1.0f + (float)cnt[i]);  // self-loop included
}

__global__ void k_scan_p1(const int* __restrict__ cnt, int* __restrict__ part, int n) {
  __shared__ int red[256];
  int tid = threadIdx.x;
  long base = (long)blockIdx.x * 1024 + tid * 4;
  int s = 0;
#pragma unroll
  for (int i = 0; i < 4; ++i) {
    long j = base + i;
    if (j < n) s += cnt[j];
  }
  red[tid] = s;
  __syncthreads();
  for (int off = 128; off; off >>= 1) {
    if (tid < off) red[tid] += red[tid + off];
    __syncthreads();
  }
  if (tid == 0) part[blockIdx.x] = red[0];
}

__global__ void k_scan_p2(int* __restrict__ part, int nb) {
  __shared__ int a[1024], b_[1024];
  int t = threadIdx.x;
  a[t] = (t < nb) ? part[t] : 0;
  __syncthreads();
  int* s = a;
  int* d = b_;
  for (int off = 1; off < 1024; off <<= 1) {
    d[t] = s[t] + ((t >= off) ? s[t - off] : 0);
    __syncthreads();
    int* tmp = s;
    s = d;
    d = tmp;
  }
  if (t < nb) part[t] = (t == 0) ? 0 : s[t - 1];  // exclusive
}

__global__ void k_scan_p3(int* __restrict__ rs, const int* __restrict__ part, int n) {
  __shared__ int a[256], b_[256];
  int tid = threadIdx.x;
  long base = (long)blockIdx.x * 1024 + tid * 4;
  int v[4];
#pragma unroll
  for (int i = 0; i < 4; ++i) {
    long j = base + i;
    v[i] = (j < n) ? rs[j] : 0;
  }
  a[tid] = v[0] + v[1] + v[2] + v[3];
  __syncthreads();
  int* s = a;
  int* d = b_;
  for (int off = 1; off < 256; off <<= 1) {
    d[tid] = s[tid] + ((tid >= off) ? s[tid - off] : 0);
    __syncthreads();
    int* t2 = s;
    s = d;
    d = t2;
  }
  int run = part[blockIdx.x] + ((tid == 0) ? 0 : s[tid - 1]);
#pragma unroll
  for (int i = 0; i < 4; ++i) {
    long j = base + i;
    if (j < n) {
      rs[j] = run;
      run += v[i];
    }
  }
}

// scatter with rowStart-shift trick: after this, rs[d] == exclusive_end(d)
__global__ void k_scatter(const int* __restrict__ src, const int* __restrict__ dst,
                          int* __restrict__ rs, int* __restrict__ csr, int E) {
  int e = blockIdx.x * blockDim.x + threadIdx.x;
  if (e < E) {
    int pos = atomicAdd(&rs[dst[e]], 1);
    __builtin_nontemporal_store(src[e], &csr[pos]);
  }
}

// ====== GCN layer-1 matmul: M = dis*(X@W), f32 in, bf16 out (K=30) =========
template <int K, bool ACT>
__global__ __launch_bounds__(256) void k_mm(const void* __restrict__ Xv,
                                            const float* __restrict__ W,
                                            const float* __restrict__ bprev,
                                            const float* __restrict__ dis,
                                            unsigned short* __restrict__ M, int n) {
  __shared__ __align__(16) float hT[K][68];
  __shared__ __align__(16) float Ws[K * 64];
  __shared__ float disS[64];
  int tid = threadIdx.x;
  int rb = blockIdx.x * 64;
  for (int j = tid; j < K * 16; j += 256) ((float4*)Ws)[j] = ((const float4*)W)[j];
  if (tid < 64) disS[tid] = (rb + tid < n) ? dis[rb + tid] : 0.0f;
  __syncthreads();
  if constexpr (ACT) {
    const unsigned short* X = (const unsigned short*)Xv;
    int k = tid & 63;
    float bk = bprev[k];
#pragma unroll
    for (int r = tid >> 6; r < 64; r += 4) {
      float h = 0.0f;
      if (rb + r < n) {
        float raw = bfu2f(X[(long)(rb + r) * 64 + k]);
        h = fmaxf(fmaf(raw, disS[r], bk), 0.0f);
      }
      hT[k][r] = h;
    }
  } else {
    const float* X = (const float*)Xv;
    for (int idx = tid; idx < 64 * K; idx += 256) {
      int r = idx / K, k = idx - r * K;
      hT[k][r] = (rb + r < n) ? X[(long)(rb + r) * K + k] : 0.0f;
    }
  }
  __syncthreads();
  int rt = (tid & 15) * 4;
  int ct = (tid >> 4) * 4;
  float acc[4][4] = {};
#pragma unroll 5
  for (int k = 0; k < K; ++k) {
    float4 xr = *(const float4*)&hT[k][rt];
    float4 wr = *(const float4*)&Ws[k * 64 + ct];
    float xa[4] = {xr.x, xr.y, xr.z, xr.w};
    float wa[4] = {wr.x, wr.y, wr.z, wr.w};
#pragma unroll
    for (int i = 0; i < 4; ++i)
#pragma unroll
      for (int j = 0; j < 4; ++j) acc[i][j] = fmaf(xa[i], wa[j], acc[i][j]);
  }
#pragma unroll
  for (int i = 0; i < 4; ++i) {
    int row = rb + rt + i;
    if (row >= n) break;
    float dv = disS[rt + i];
    ushort4 pk;
    pk.x = f2bfu(acc[i][0] * dv);
    pk.y = f2bfu(acc[i][1] * dv);
    pk.z = f2bfu(acc[i][2] * dv);
    pk.w = f2bfu(acc[i][3] * dv);
    *(ushort4*)&M[(long)row * 64 + ct] = pk;
  }
}

// ===== fused gather+act+MFMA: Mout = dis * (relu((agg Min)*dis + b) @ W) ====
// Block = 64 nodes. Wave wv gathers rows [wv*16, wv*16+16) in 4 passes of 4
// nodes (16 lanes x uint2 per row), writes relu-activated bf16 rows into the
// swizzled LDS A-tile; then the k_mmg MFMA phase (Bt = W^T) and dis-scaled
// write of Mout.
__global__ __launch_bounds__(256) void k_gmm(
    const int* __restrict__ rs, const int* __restrict__ csr,
    const unsigned short* __restrict__ Min, const float* __restrict__ dis,
    const float* __restrict__ bias, const float* __restrict__ W,
    unsigned short* __restrict__ Mout, int n) {
  __shared__ __align__(16) unsigned short As[64 * 64];
  __shared__ __align__(16) unsigned short Bt[64 * 64];
  const int tid = threadIdx.x;
  const int bm = blockIdx.x * 64;
  // ---- stage Bt[n][k] = W[k][n] bf16, swizzled
  {
    int nn = tid & 63, k0 = (tid >> 6) * 16;
    bf16x8 v0, v1;
#pragma unroll
    for (int i = 0; i < 8; ++i) v0[i] = (short)f2bfu(W[(size_t)(k0 + i) * 64 + nn]);
#pragma unroll
    for (int i = 0; i < 8; ++i) v1[i] = (short)f2bfu(W[(size_t)(k0 + 8 + i) * 64 + nn]);
    int off0 = (nn * 128 + k0 * 2) ^ ((nn & 7) << 4);
    int off1 = (nn * 128 + (k0 + 8) * 2) ^ ((nn & 7) << 4);
    *(bf16x8*)((char*)Bt + off0) = v0;
    *(bf16x8*)((char*)Bt + off1) = v1;
  }
  // ---- gather + act into As
  const int lane = tid & 63;
  const int wv = tid >> 6;
  const int grp = lane >> 4, l16 = lane & 15;
  const float4 bb = *(const float4*)(bias + l16 * 4);
  for (int p = 0; p < 4; ++p) {
    int local = wv * 16 + p * 4 + grp;
    int node = bm + local;
    float a0 = 0.f, a1 = 0.f, a2 = 0.f, a3 = 0.f;
    float c0 = 0.f, c1 = 0.f, c2 = 0.f, c3 = 0.f;
    float dv = 0.f;
    if (node < n) {
      uint2 v = *(const uint2*)(Min + (size_t)node * 64 + l16 * 4);  // self loop
      a0 = bfu2f(v.x & 0xffffu);
      a1 = bfu2f(v.x >> 16);
      a2 = bfu2f(v.y & 0xffffu);
      a3 = bfu2f(v.y >> 16);
      int start = (node == 0) ? 0 : rs[node - 1];
      int end = rs[node];
      int j = start;
      for (; j + 1 < end; j += 2) {
        int s0 = csr[j], s1 = csr[j + 1];
        uint2 u = *(const uint2*)(Min + (size_t)s0 * 64 + l16 * 4);
        uint2 w2 = *(const uint2*)(Min + (size_t)s1 * 64 + l16 * 4);
        a0 += bfu2f(u.x & 0xffffu);
        a1 += bfu2f(u.x >> 16);
        a2 += bfu2f(u.y & 0xffffu);
        a3 += bfu2f(u.y >> 16);
        c0 += bfu2f(w2.x & 0xffffu);
        c1 += bfu2f(w2.x >> 16);
        c2 += bfu2f(w2.y & 0xffffu);
        c3 += bfu2f(w2.y >> 16);
      }
      if (j < end) {
        uint2 u = *(const uint2*)(Min + (size_t)csr[j] * 64 + l16 * 4);
        a0 += bfu2f(u.x & 0xffffu);
        a1 += bfu2f(u.x >> 16);
        a2 += bfu2f(u.y & 0xffffu);
        a3 += bfu2f(u.y >> 16);
      }
      dv = dis[node];
    }
    ushort4 h;
    h.x = f2bfu(fmaxf(fmaf(a0 + c0, dv, bb.x), 0.f));
    h.y = f2bfu(fmaxf(fmaf(a1 + c1, dv, bb.y), 0.f));
    h.z = f2bfu(fmaxf(fmaf(a2 + c2, dv, bb.z), 0.f));
    h.w = f2bfu(fmaxf(fmaf(a3 + c3, dv, bb.w), 0.f));
    int off = (local * 128 + l16 * 8) ^ ((local & 7) << 4);
    *(ushort4*)((char*)As + off) = h;
  }
  __syncthreads();
  // ---- MFMA phase (identical to k_mmg)
  const int kb = lane >> 4, fr = lane & 15;
  f32x4 acc[4];
#pragma unroll
  for (int i = 0; i < 4; ++i) acc[i] = f32x4{0.f, 0.f, 0.f, 0.f};
  const int ar = wv * 16 + fr;
#pragma unroll
  for (int kc = 0; kc < 2; ++kc) {
    int aoff = (ar * 128 + kc * 64 + kb * 16) ^ ((ar & 7) << 4);
    bf16x8 a = *(const bf16x8*)((char*)As + aoff);
#pragma unroll
    for (int ni = 0; ni < 4; ++ni) {
      int nr = ni * 16 + fr;
      int boff = (nr * 128 + kc * 64 + kb * 16) ^ ((nr & 7) << 4);
      bf16x8 b = *(const bf16x8*)((char*)Bt + boff);
      acc[ni] = __builtin_amdgcn_mfma_f32_16x16x32_bf16(a, b, acc[ni], 0, 0, 0);
    }
  }
#pragma unroll
  for (int r = 0; r < 4; ++r) {
    int row = bm + wv * 16 + kb * 4 + r;
    if (row < n) {
      float dvo = dis[row];
#pragma unroll
      for (int ni = 0; ni < 4; ++ni)
        Mout[(size_t)row * 64 + ni * 16 + fr] = f2bfu(acc[ni][r] * dvo);
    }
  }
}

// == gather+act: H[d] = relu((M[d] + sum_{s in csr[d]} M[s]) * dis[d] + b) ==
__global__ void k_gather_act(const int* __restrict__ rs, const int* __restrict__ csr,
                             const unsigned short* __restrict__ M,
                             const float* __restrict__ dis, const float* __restrict__ bias,
                             unsigned short* __restrict__ H, int n) {
  int w = (int)((blockIdx.x * (long)blockDim.x + threadIdx.x) >> 6);
  int lane = threadIdx.x & 63;
  int grp = lane >> 4, l16 = lane & 15;
  int node = w * 4 + grp;
  bool act = node < n;
  int start = 0, end = 0;
  if (act) {
    start = (node == 0) ? 0 : rs[node - 1];
    end = rs[node];
  }
  float a0 = 0.f, a1 = 0.f, a2 = 0.f, a3 = 0.f;
  float c0 = 0.f, c1 = 0.f, c2 = 0.f, c3 = 0.f;
  if (act) {
    uint2 v = *(const uint2*)(M + (size_t)node * 64 + l16 * 4);  // self loop
    a0 = bfu2f(v.x & 0xffffu);
    a1 = bfu2f(v.x >> 16);
    a2 = bfu2f(v.y & 0xffffu);
    a3 = bfu2f(v.y >> 16);
  }
  int j = start;
  for (; j + 1 < end; j += 2) {
    int s0 = csr[j], s1 = csr[j + 1];
    uint2 u = *(const uint2*)(M + (size_t)s0 * 64 + l16 * 4);
    uint2 v = *(const uint2*)(M + (size_t)s1 * 64 + l16 * 4);
    a0 += bfu2f(u.x & 0xffffu);
    a1 += bfu2f(u.x >> 16);
    a2 += bfu2f(u.y & 0xffffu);
    a3 += bfu2f(u.y >> 16);
    c0 += bfu2f(v.x & 0xffffu);
    c1 += bfu2f(v.x >> 16);
    c2 += bfu2f(v.y & 0xffffu);
    c3 += bfu2f(v.y >> 16);
  }
  if (j < end) {
    uint2 u = *(const uint2*)(M + (size_t)csr[j] * 64 + l16 * 4);
    a0 += bfu2f(u.x & 0xffffu);
    a1 += bfu2f(u.x >> 16);
    a2 += bfu2f(u.y & 0xffffu);
    a3 += bfu2f(u.y >> 16);
  }
  if (act) {
    float dv = dis[node];
    float4 bb = *(const float4*)(bias + l16 * 4);
    ushort4 o;
    o.x = f2bfu(fmaxf(fmaf(a0 + c0, dv, bb.x), 0.f));
    o.y = f2bfu(fmaxf(fmaf(a1 + c1, dv, bb.y), 0.f));
    o.z = f2bfu(fmaxf(fmaf(a2 + c2, dv, bb.z), 0.f));
    o.w = f2bfu(fmaxf(fmaf(a3 + c3, dv, bb.w), 0.f));
    *(ushort4*)(H + (size_t)node * 64 + l16 * 4) = o;
  }
}

// ============ mean pool over sorted batch (H already post-relu) =============
__global__ void k_pool8(const unsigned short* __restrict__ H, const int* __restrict__ batch,
                        float* __restrict__ sums, float* __restrict__ cntf, int n) {
  int w = (int)((blockIdx.x * (long)blockDim.x + threadIdx.x) >> 6);
  int lane = threadIdx.x & 63;
  int r0 = w * 8;
  if (r0 >= n) return;
  int cur = batch[r0];
  float acc = bfu2f(H[(long)r0 * 64 + lane]);
  float c = 1.0f;
  for (int i = 1; i < 8; ++i) {
    int r = r0 + i;
    if (r >= n) break;
    int b = batch[r];
    float v = bfu2f(H[(long)r * 64 + lane]);
    if (b == cur) {
      acc += v;
      c += 1.0f;
    } else {
      unsafeAtomicAdd(&sums[(long)cur * 64 + lane], acc);
      if (lane == 0) unsafeAtomicAdd(&cntf[cur], c);
      cur = b;
      acc = v;
      c = 1.0f;
    }
  }
  unsafeAtomicAdd(&sums[(long)cur * 64 + lane], acc);
  if (lane == 0) unsafeAtomicAdd(&cntf[cur], c);
}

// ================= drug fc: relu((sums/cnt) @ Wd + bd), 64 -> 128 ===========
__global__ void k_drugfc(const float* __restrict__ sums, const float* __restrict__ cnt,
                         const float* __restrict__ W, const float* __restrict__ b,
                         float* __restrict__ out, int B) {
  __shared__ float ps[64];
  int row = blockIdx.x;
  int tid = threadIdx.x;
  float inv = 1.0f / fmaxf(cnt[row], 1.0f);
  if (tid < 64) ps[tid] = sums[(long)row * 64 + tid] * inv;
  __syncthreads();
  float acc = b[tid];
#pragma unroll 8
  for (int k = 0; k < 64; ++k) acc = fmaf(ps[k], W[k * 128 + tid], acc);
  out[(long)row * 128 + tid] = fmaxf(acc, 0.0f);
}

// ============ f32 [M x Kin] -> bf16 [M x ldout], zero-padded cols ===========
__global__ void k_cvt_bf16(const float* __restrict__ X, unsigned short* __restrict__ Y,
                           int Kin, int ldout) {
  int row = blockIdx.x;
  const float* xr = X + (size_t)row * Kin;
  unsigned short* yr = Y + (size_t)row * ldout;
  for (int j = threadIdx.x; j < ldout; j += 256)
    yr[j] = (j < Kin) ? f2bfu(xr[j]) : 0;
}

// ===== bf16 MFMA GEMM, 64x128 tile, BK=32, reg-prefetch double-buffer ======
template <bool SPLIT, typename OT>
__global__ __launch_bounds__(256, 3) void k_gemm2(
    const unsigned short* __restrict__ A, const float* __restrict__ W,
    const float* __restrict__ bias, OT* __restrict__ C,
    int Mrows, int N, int K, int lda, int nsteps, int chunkSteps) {
  __shared__ __align__(16) unsigned short As[2][64 * 32];
  __shared__ __align__(16) unsigned short Bs[2][128 * 32];
  const int tid = threadIdx.x;
  const int lane = tid & 63;
  const int wid = tid >> 6;
  const int bm = blockIdx.x * 64;
  const int bn = blockIdx.y * 128;
  const int kb = lane >> 4, fr = lane & 15;
  const int ss0 = blockIdx.z * chunkSteps;
  const int ss1 = min(nsteps, ss0 + chunkSteps);

  f32x4 acc[8];
#pragma unroll
  for (int j = 0; j < 8; ++j) acc[j] = f32x4{0.f, 0.f, 0.f, 0.f};

  const int ar = wid * 16 + fr;
  const int aOff = (ar * 64 + kb * 16) ^ ((ar & 7) << 4);
  int bOff[8];
#pragma unroll
  for (int ni = 0; ni < 8; ++ni) {
    int nr = ni * 16 + fr;
    bOff[ni] = (nr * 64 + kb * 16) ^ ((nr & 7) << 4);
  }
  const int arow = tid >> 2, ac = tid & 3;
  const int aW = (arow * 64 + ac * 16) ^ ((arow & 7) << 4);
  const int bn_ = tid & 127, bk0 = (tid >> 7) * 2;
  int bW[2];
#pragma unroll
  for (int p = 0; p < 2; ++p) {
    int kbb = bk0 + p;
    bW[p] = (bn_ * 64 + kbb * 16) ^ ((bn_ & 7) << 4);
  }

  bf16x8 pa;
  float pb[2][8];
  const unsigned short* aptr = A + (size_t)(bm + arow) * lda + ac * 8;

#define LOAD_STEP(S)                                              \
  {                                                               \
    int k0 = (S) * 32;                                            \
    pa = *(const bf16x8*)(aptr + k0);                             \
    _Pragma("unroll") for (int p = 0; p < 2; ++p) {               \
      _Pragma("unroll") for (int i = 0; i < 8; ++i) {             \
        int gk = k0 + (bk0 + p) * 8 + i;                          \
        pb[p][i] = (gk < K) ? W[(size_t)gk * N + bn + bn_] : 0.f; \
      }                                                           \
    }                                                             \
  }
#define STORE_STEP(BUF)                                           \
  {                                                               \
    *(bf16x8*)((char*)As[BUF] + aW) = pa;                         \
    _Pragma("unroll") for (int p = 0; p < 2; ++p) {               \
      bf16x8 v;                                                   \
      _Pragma("unroll") for (int i = 0; i < 8; ++i)               \
          v[i] = (short)f2bfu(pb[p][i]);                          \
      *(bf16x8*)((char*)Bs[BUF] + bW[p]) = v;                     \
    }                                                             \
  }

  LOAD_STEP(ss0);
  STORE_STEP(0);
  __syncthreads();
  int cur = 0;
  for (int s = ss0; s < ss1; ++s) {
    bool more = (s + 1 < ss1);
    if (more) LOAD_STEP(s + 1);
    bf16x8 a0 = *(const bf16x8*)((char*)As[cur] + aOff);
#pragma unroll
    for (int ni = 0; ni < 8; ++ni) {
      bf16x8 b = *(const bf16x8*)((char*)Bs[cur] + bOff[ni]);
      acc[ni] = __builtin_amdgcn_mfma_f32_16x16x32_bf16(a0, b, acc[ni], 0, 0, 0);
    }
    if (more) {
      STORE_STEP(cur ^ 1);
      __syncthreads();
      cur ^= 1;
    }
  }
  if constexpr (SPLIT) {
    float* Cz = (float*)C + (size_t)blockIdx.z * Mrows * N;
#pragma unroll
    for (int ni = 0; ni < 8; ++ni)
#pragma unroll
      for (int r = 0; r < 4; ++r) {
        int row = bm + wid * 16 + kb * 4 + r;
        int col = bn + ni * 16 + fr;
        Cz[(size_t)row * N + col] = acc[ni][r];
      }
  } else {
    float bv[8];
#pragma unroll
    for (int ni = 0; ni < 8; ++ni) bv[ni] = bias[bn + ni * 16 + fr];
#pragma unroll
    for (int ni = 0; ni < 8; ++ni)
#pragma unroll
      for (int r = 0; r < 4; ++r) {
        int row = bm + wid * 16 + kb * 4 + r;
        int col = bn + ni * 16 + fr;
        float x = fmaxf(acc[ni][r] + bv[ni], 0.f);
        if constexpr (__hip_internal::is_same<OT, float>::value) {
          C[(size_t)row * N + col] = x;
        } else {
          C[(size_t)row * N + col] = f2bfu(x);
        }
      }
  }
#undef LOAD_STEP
#undef STORE_STEP
}

// ---- concat + LayerNorm; prot = relu(sum of 4 K-split partials + bp) -------
__global__ void k_concat_ln(const float* __restrict__ drug, const float* __restrict__ protP,
                            const float* __restrict__ bp, const float* __restrict__ fpp,
                            unsigned short* __restrict__ comb, int B) {
  __shared__ float buf[CONCAT_F];
  __shared__ float rs[4], rs2[4];
  int row = blockIdx.x;
  int tid = threadIdx.x;
  const size_t MN = (size_t)B * 128;
  float s = 0.0f, s2 = 0.0f;
  for (int j = tid; j < CONCAT_F; j += 256) {
    float v;
    if (j < 128) {
      v = drug[(long)row * 128 + j];
    } else if (j < 256) {
      int c = j - 128;
      size_t o = (size_t)row * 128 + c;
      float acc = protP[o] + protP[MN + o] + protP[2 * MN + o] + protP[3 * MN + o];
      v = fmaxf(acc + bp[c], 0.0f);
    } else {
      v = fpp[(long)row * 881 + (j - 256)];
    }
    buf[j] = v;
    s += v;
    s2 += v * v;
  }
  for (int o = 32; o; o >>= 1) {
    s += __shfl_down(s, o, 64);
    s2 += __shfl_down(s2, o, 64);
  }
  int lane = tid & 63, wid = tid >> 6;
  if (lane == 0) { rs[wid] = s; rs2[wid] = s2; }
  __syncthreads();
  if (tid == 0) {
    float ts = rs[0] + rs[1] + rs[2] + rs[3];
    float ts2 = rs2[0] + rs2[1] + rs2[2] + rs2[3];
    float mu = ts / (float)CONCAT_F;
    float var = ts2 / (float)CONCAT_F - mu * mu;
    rs[0] = mu;
    rs2[0] = rsqrtf(fmaxf(var, 0.0f) + 1e-5f);
  }
  __syncthreads();
  float mu = rs[0], inv = rs2[0];
  for (int j = tid; j < CONCAT_P; j += 256) {
    unsigned short o = (j < CONCAT_F) ? f2bfu((buf[j] - mu) * inv) : 0;
    comb[(long)row * CONCAT_P + j] = o;
  }
}

// ---------------- fc3: X @ w + b, 256 -> 1 ----------------------------------
__global__ void k_fc3(const float* __restrict__ X, const float* __restrict__ W,
                      const float* __restrict__ bias, float* __restrict__ out, int B) {
  int w = (int)((blockIdx.x * (long)blockDim.x + threadIdx.x) >> 6);
  int lane = threadIdx.x & 63;
  if (w >= B) return;
  float s = 0.0f;
#pragma unroll
  for (int j = 0; j < 4; ++j) s = fmaf(X[(long)w * 256 + lane + j * 64], W[lane + j * 64], s);
  for (int o = 32; o; o >>= 1) s += __shfl_down(s, o, 64);
  if (lane == 0) out[w] = s + bias[0];
}

// ---------------------------------------------------------------------------
extern "C" void kernel_launch(void* const* d_in, const int* in_sizes, int n_in,
                              void* d_out, int out_size, void* d_ws, size_t ws_size,
                              hipStream_t stream) {
  const float* drug_x = (const float*)d_in[0];
  const int* ei = (const int*)d_in[1];
  const int* batch = (const int*)d_in[2];
  const float* protein_x = (const float*)d_in[3];
  const float* fpp = (const float*)d_in[4];
  const float* W1 = (const float*)d_in[5];
  const float* b1 = (const float*)d_in[6];
  const float* W2 = (const float*)d_in[7];
  const float* b2 = (const float*)d_in[8];
  const float* W3 = (const float*)d_in[9];
  const float* b3 = (const float*)d_in[10];
  const float* Wd = (const float*)d_in[11];
  const float* bd = (const float*)d_in[12];
  const float* Wp = (const float*)d_in[13];
  const float* bp = (const float*)d_in[14];
  const float* Wf1 = (const float*)d_in[15];
  const float* bf1 = (const float*)d_in[16];
  const float* Wf2 = (const float*)d_in[17];
  const float* bf2 = (const float*)d_in[18];
  const float* Wf3 = (const float*)d_in[19];
  const float* bf3 = (const float*)d_in[20];
  float* out = (float*)d_out;

  const int N = in_sizes[0] / 30;
  const int E = in_sizes[1] / 2;
  const int B = in_sizes[4] / 881;

  // ---- GCN-phase workspace (4-byte words) ----
  int* rs = (int*)d_ws;
  float* dis = (float*)d_ws + ((size_t)N + 1);
  int* csr = (int*)d_ws + (2 * (size_t)N + 1);
  size_t oM = 2 * (size_t)N + 2 + (size_t)E;
  unsigned short* M = (unsigned short*)((float*)d_ws + oM);
  unsigned short* H = M + (size_t)N * 64;
  float* sums = (float*)d_ws + (oM + 64 * (size_t)N);
  float* cntf = sums + (size_t)B * 64;
  int* part = (int*)(cntf + B);
  unsigned short* protbh = (unsigned short*)(part + 1024);  // B*PROT_P bf16
  // ---- dense-tail aliases at offset 0 (GCN buffers dead by then) ----
  float* tail = (float*)d_ws;
  float* drug = tail;                                        // B*128 f32
  float* protP = drug + (size_t)B * 128;                     // 4*B*128 f32 partials
  unsigned short* combh = (unsigned short*)(protP + 4 * (size_t)B * 128);  // B*1152 bf16
  unsigned short* act1h = combh + (size_t)B * CONCAT_P;      // B*512 bf16
  float* act2 = (float*)(act1h + (size_t)B * 512);           // B*256 f32

  const int* srcIdx = ei;
  const int* dstIdx = ei + E;

  // ---- protein f32 -> bf16 ----
  k_cvt_bf16<<<B, 256, 0, stream>>>(protein_x, protbh, PROT_K, PROT_P);

  // ---- CSR build + degree ----
  hipMemsetAsync(rs, 0, ((size_t)N + 1) * sizeof(int), stream);
  k_count<<<(E + 255) / 256, 256, 0, stream>>>(dstIdx, rs, E);
  k_disk<<<(N + 255) / 256, 256, 0, stream>>>(rs, dis, N);
  int NB = (N + 1023) / 1024;
  k_scan_p1<<<NB, 256, 0, stream>>>(rs, part, N);
  k_scan_p2<<<1, 1024, 0, stream>>>(part, NB);
  k_scan_p3<<<NB, 256, 0, stream>>>(rs, part, N);
  k_scatter<<<(E + 255) / 256, 256, 0, stream>>>(srcIdx, dstIdx, rs, csr, E);

  // ---- GCN layers ----
  int mmBlocks = (N + 63) / 64;
  int gWaves = (N + 3) / 4;
  int gBlocks = (gWaves + 3) / 4;
  k_mm<30, false><<<mmBlocks, 256, 0, stream>>>(drug_x, W1, nullptr, dis, M, N);
  k_gmm<<<mmBlocks, 256, 0, stream>>>(rs, csr, M, dis, b1, W2, H, N);  // H = M2
  k_gmm<<<mmBlocks, 256, 0, stream>>>(rs, csr, H, dis, b2, W3, M, N);  // M = M3
  k_gather_act<<<gBlocks, 256, 0, stream>>>(rs, csr, M, dis, b3, H, N);

  // ---- mean pool ----
  hipMemsetAsync(sums, 0, ((size_t)B * 64 + B) * sizeof(float), stream);
  int poolWaves = (N + 7) / 8;
  k_pool8<<<(poolWaves + 3) / 4, 256, 0, stream>>>(H, batch, sums, cntf, N);

  // ---- dense tail ----
  k_drugfc<<<B, 128, 0, stream>>>(sums, cntf, Wd, bd, drug, B);
  k_gemm2<true, float><<<dim3(B / 64, 1, 4), 256, 0, stream>>>(
      protbh, Wp, nullptr, protP, B, 128, PROT_K, PROT_P, 31, 8);
  k_concat_ln<<<B, 256, 0, stream>>>(drug, protP, bp, fpp, combh, B);
  k_gemm2<false, unsigned short><<<dim3(B / 64, 4, 1), 256, 0, stream>>>(
      combh, Wf1, bf1, act1h, B, 512, CONCAT_F, CONCAT_P, 36, 36);
  k_gemm2<false, float><<<dim3(B / 64, 2, 1), 256, 0, stream>>>(
      act1h, Wf2, bf2, act2, B, 256, 512, 512, 16, 16);
  k_fc3<<<(B + 3) / 4, 256, 0, stream>>>(act2, Wf3, bf3, out, B);
}